// Round 7
// baseline (357.385 us; speedup 1.0000x reference)
//
#include <hip/hip_runtime.h>
#include <math.h>

typedef unsigned int u32;
typedef unsigned short u16;
typedef __attribute__((ext_vector_type(8))) short bf16x8;   // 8 bf16 in 4 VGPRs
typedef __attribute__((ext_vector_type(4))) float f32x4;

__device__ inline u16 f2bf(float x) {  // round-to-nearest-even
    union { float f; u32 u; } v; v.f = x;
    u32 r = v.u + 0x7FFFu + ((v.u >> 16) & 1u);
    return (u16)(r >> 16);
}
__device__ inline float4 bf4_to_f4(uint2 p) {
    float4 r;
    r.x = __uint_as_float(p.x << 16);
    r.y = __uint_as_float(p.x & 0xffff0000u);
    r.z = __uint_as_float(p.y << 16);
    r.w = __uint_as_float(p.y & 0xffff0000u);
    return r;
}

// ---------------------------------------------------------------------------
// Clifford GNN message passing, fully linearized:
//   agg[n] = sum_e w_e*(h[src] .* r[rel]),  w_e = gate(rel)*norm(e)
//   out    = (Ku.Km).agg + Ku.h + ws*(Ku.msg_b) + upd_b
// One K=512 register-blocked MFMA GEMM on [agg_row | h_row], Kcomb=[Ku.Km|Ku]
// rows pre-permuted to make the output store channel-major-coalesced.
// GEMM: no LDS/barriers; wave tile 32x64 (acc 2x4 frags = 32 AGPR) so
// ~4 waves/SIMD can co-reside and hide global-load latency (round-6
// post-mortem: 64x64 tile -> 160 regs -> 3 waves/SIMD -> 18% occupancy).
// ---------------------------------------------------------------------------

// Mf[k*256+i] = M[k][i] fp32 (message Clifford matrix, row k = output idx)
__global__ void build_m_kernel(const float* __restrict__ msg_w, float* __restrict__ Mf) {
    const int   s_tab[16] = {0,1,2,3, 1,0,3,2, 2,3,0,1, 3,2,1,0};
    const float g_tab[16] = {1.f,1.f,1.f,-1.f, 1.f,1.f,-1.f,1.f,
                             1.f,1.f,1.f,-1.f, 1.f,1.f,1.f,1.f};
    int idx = blockIdx.x * 256 + threadIdx.x;   // idx = k*256 + i
    int k = idx >> 8, i = idx & 255;
    int ob = k >> 6, oc = k & 63, ib = i >> 6, ic = i & 63;
    int t = ob * 4 + ib;
    Mf[idx] = g_tab[t] * msg_w[s_tab[t] * 4096 + oc * 64 + ic];
}

// Block p builds output-permuted row p of Kcomb (512 wide bf16) + c0[p], c1[p].
// j = (p&3)*64 + (p>>2);  Kcomb[p][0:256] = (U.M)[j][:], Kcomb[p][256:512]=U[j][:]
__global__ __launch_bounds__(256) void build_comb_kernel(
    const float* __restrict__ upd_w, const float* __restrict__ upd_b,
    const float* __restrict__ msg_b, const float* __restrict__ Mf,
    u16* __restrict__ Kcomb, float* __restrict__ c0, float* __restrict__ c1) {
    const int   s_tab[16] = {0,1,2,3, 1,0,3,2, 2,3,0,1, 3,2,1,0};
    const float g_tab[16] = {1.f,1.f,1.f,-1.f, 1.f,1.f,-1.f,1.f,
                             1.f,1.f,1.f,-1.f, 1.f,1.f,1.f,1.f};
    __shared__ float U_s[256];
    __shared__ float wred[4];
    int p = blockIdx.x;
    int j = (p & 3) * 64 + (p >> 2);
    int tid = threadIdx.x;
    {
        int ob = j >> 6, oc = j & 63, ib = tid >> 6, ic = tid & 63;
        int t = ob * 4 + ib;
        U_s[tid] = g_tab[t] * upd_w[s_tab[t] * 4096 + oc * 64 + ic];
    }
    __syncthreads();
    float acc = 0.f;
#pragma unroll 8
    for (int k = 0; k < 256; ++k) acc += U_s[k] * Mf[k * 256 + tid];
    Kcomb[(size_t)p * 512 + tid] = f2bf(acc);
    Kcomb[(size_t)p * 512 + 256 + tid] = f2bf(U_s[tid]);
    float part = U_s[tid] * msg_b[tid];
    int lane = tid & 63, wv = tid >> 6;
#pragma unroll
    for (int d = 32; d > 0; d >>= 1) part += __shfl_down(part, d);
    if (lane == 0) wred[wv] = part;
    __syncthreads();
    if (tid == 0) { c1[p] = wred[0] + wred[1] + wred[2] + wred[3]; c0[p] = upd_b[j]; }
}

// gate[r] = sigmoid( sum_j rel_emb[r, j] * gate_w[(j&63)*4 + (j>>6)] + gate_b )
__global__ void gate_kernel(const float* __restrict__ rel_emb,
                            const float* __restrict__ gate_w,
                            const float* __restrict__ gate_b,
                            float* __restrict__ gate, int R) {
    int wv = threadIdx.x >> 6, lane = threadIdx.x & 63;
    int r = blockIdx.x * 4 + wv;
    if (r >= R) return;
    float4 rv = *(const float4*)(rel_emb + (size_t)r * 256 + lane * 4);
    float s = 0.f;
    float rvv[4] = {rv.x, rv.y, rv.z, rv.w};
#pragma unroll
    for (int c = 0; c < 4; ++c) {
        int j = lane * 4 + c;
        s += rvv[c] * gate_w[(j & 63) * 4 + (j >> 6)];
    }
#pragma unroll
    for (int d = 32; d > 0; d >>= 1) s += __shfl_down(s, d);
    if (lane == 0) gate[r] = 1.0f / (1.0f + expf(-(s + gate_b[0])));
}

__global__ void degree_kernel(const int* __restrict__ ei, int E,
                              u32* __restrict__ deg_src, u32* __restrict__ deg_dst) {
    int e = blockIdx.x * 256 + threadIdx.x;
    if (e >= E) return;
    atomicAdd(&deg_src[ei[e]], 1u);
    atomicAdd(&deg_dst[ei[E + e]], 1u);
}

// Parallel bucket allocator (order irrelevant, only disjointness matters).
__global__ void alloc_kernel(const u32* __restrict__ deg, u32* __restrict__ offs,
                             u32* __restrict__ cursor, u32* __restrict__ total, int N) {
    __shared__ u32 wt[4];
    __shared__ u32 bbase;
    int tid = threadIdx.x, lane = tid & 63, wv = tid >> 6;
    int i = blockIdx.x * 256 + tid;
    u32 d = (i < N) ? deg[i] : 0u;
    u32 sc = d;
#pragma unroll
    for (int s = 1; s < 64; s <<= 1) { u32 o = __shfl_up(sc, s); if (lane >= s) sc += o; }
    if (lane == 63) wt[wv] = sc;
    __syncthreads();
    if (tid == 0) bbase = atomicAdd(total, wt[0] + wt[1] + wt[2] + wt[3]);
    __syncthreads();
    u32 wpre = 0;
    for (int w = 0; w < wv; ++w) wpre += wt[w];
    u32 off = bbase + wpre + sc - d;
    if (i < N) { offs[i] = off; cursor[i] = off; }
}

// Bucket-fill, packed metadata: edata[pos] = {src, rel, w_bits, 0}.
__global__ void fill_kernel(const int* __restrict__ ei, const int* __restrict__ et,
                            const u32* __restrict__ deg_src,
                            const u32* __restrict__ deg_dst,
                            const float* __restrict__ gate,
                            u32* __restrict__ cursor, uint4* __restrict__ edata, int E) {
    int e = blockIdx.x * 256 + threadIdx.x;
    if (e >= E) return;
    int src = ei[e];
    int dst = ei[E + e];
    int rel = et[e];
    float w = gate[rel] * rsqrtf(fmaxf((float)deg_src[src] * (float)deg_dst[dst], 1.0f));
    u32 pos = atomicAdd(&cursor[dst], 1u);
    edata[pos] = make_uint4((u32)src, (u32)rel, __float_as_uint(w), 0u);
}

// fp32 -> bf16 bulk convert (8 elems/thread, grid-stride).
__global__ void tobf_kernel(const float* __restrict__ src, u16* __restrict__ dst, int n8) {
    for (int i = blockIdx.x * 256 + threadIdx.x; i < n8; i += gridDim.x * 256) {
        const float* p = src + (size_t)i * 8;
        float4 a = *(const float4*)(p);
        float4 b = *(const float4*)(p + 4);
        u16 tmp[8] = {f2bf(a.x), f2bf(a.y), f2bf(a.z), f2bf(a.w),
                      f2bf(b.x), f2bf(b.y), f2bf(b.z), f2bf(b.w)};
        *(uint4*)(dst + (size_t)i * 8) = *(const uint4*)tmp;
    }
}

// One wave per node: agg row (bf16) into first 512B of d_out's 1KB slot + wsum.
// Edge loop unrolled x4: 4 independent edata loads + 8 gathers in flight.
template <int BF>
__global__ __launch_bounds__(256) void agg_kernel(
    const float* __restrict__ h, const u16* __restrict__ h_bf,
    const float* __restrict__ rel_emb, const u16* __restrict__ rel_bf,
    const u32* __restrict__ offs, const u32* __restrict__ deg_dst,
    const uint4* __restrict__ edata,
    u16* __restrict__ agg_bf, float* __restrict__ wsum_arr, int N) {
    int wv = threadIdx.x >> 6, lane = threadIdx.x & 63;
    int n = blockIdx.x * 4 + wv;
    if (n >= N) return;
    u32 off = offs[n];
    u32 dd = deg_dst[n];
    float4 acc = make_float4(0.f, 0.f, 0.f, 0.f);
    float wsum = 0.f;
    u32 e = 0;
    for (; e + 4 <= dd; e += 4) {
        uint4 d[4];
        float4 hv[4], rv[4];
#pragma unroll
        for (int q = 0; q < 4; ++q) d[q] = edata[off + e + q];
#pragma unroll
        for (int q = 0; q < 4; ++q) {
            if (BF) {
                hv[q] = bf4_to_f4(*(const uint2*)(h_bf + (size_t)d[q].x * 256 + lane * 4));
                rv[q] = bf4_to_f4(*(const uint2*)(rel_bf + (size_t)d[q].y * 256 + lane * 4));
            } else {
                hv[q] = *(const float4*)(h + (size_t)d[q].x * 256 + lane * 4);
                rv[q] = *(const float4*)(rel_emb + (size_t)d[q].y * 256 + lane * 4);
            }
        }
#pragma unroll
        for (int q = 0; q < 4; ++q) {
            float w = __uint_as_float(d[q].z);
            acc.x += w * hv[q].x * rv[q].x;
            acc.y += w * hv[q].y * rv[q].y;
            acc.z += w * hv[q].z * rv[q].z;
            acc.w += w * hv[q].w * rv[q].w;
            wsum += w;
        }
    }
    for (; e < dd; ++e) {
        uint4 d0 = edata[off + e];
        float w0 = __uint_as_float(d0.z);
        float4 h0, r0;
        if (BF) {
            h0 = bf4_to_f4(*(const uint2*)(h_bf + (size_t)d0.x * 256 + lane * 4));
            r0 = bf4_to_f4(*(const uint2*)(rel_bf + (size_t)d0.y * 256 + lane * 4));
        } else {
            h0 = *(const float4*)(h + (size_t)d0.x * 256 + lane * 4);
            r0 = *(const float4*)(rel_emb + (size_t)d0.y * 256 + lane * 4);
        }
        acc.x += w0 * h0.x * r0.x;
        acc.y += w0 * h0.y * r0.y;
        acc.z += w0 * h0.z * r0.z;
        acc.w += w0 * h0.w * r0.w;
        wsum += w0;
    }
    u32 lo = (u32)f2bf(acc.x) | ((u32)f2bf(acc.y) << 16);
    u32 hi = (u32)f2bf(acc.z) | ((u32)f2bf(acc.w) << 16);
    *(uint2*)(agg_bf + (size_t)n * 512 + lane * 4) = make_uint2(lo, hi);
    if (lane == 0) wsum_arr[n] = wsum;
}

// Register-blocked K=512 GEMM, NO LDS, NO barriers. Block = 32 rows, 4 waves;
// wave = 32 rows x 64 cols (acc 2x4 frags = 32 AGPR, ~96 regs total ->
// 4+ waves/SIMD with launch_bounds(256,4)). A-frags direct from global
// (agg slots in d_out at 1KB stride, then h_bf); each A-load = 16 rows x 64B.
// out[row][p] = acc + c0[p] + c1[p]*wsum[row]  (Kcomb rows output-permuted).
template <int BF>
__global__ __launch_bounds__(256, 4) void gemm_reg_kernel(
    float* __restrict__ dio, const u16* __restrict__ agg_bf,
    const u16* __restrict__ Kcomb,
    const float* __restrict__ h, const u16* __restrict__ h_bf,
    const float* __restrict__ wsum_arr,
    const float* __restrict__ c0, const float* __restrict__ c1, int N) {
    const int lane = threadIdx.x & 63;
    const int wv = threadIdx.x >> 6;      // wave owns output cols [wv*64, +64)
    const int l15 = lane & 15;
    const int kg = lane >> 4;             // k-group 0..3
    const int m0 = blockIdx.x * 32;
    const int pbase = wv * 64;

    f32x4 acc[2][4];
#pragma unroll
    for (int f = 0; f < 2; ++f)
#pragma unroll
        for (int nf = 0; nf < 4; ++nf) acc[f][nf] = (f32x4)(0.f);

    int rowA[2];
#pragma unroll
    for (int f = 0; f < 2; ++f) {
        int r = m0 + f * 16 + l15;
        rowA[f] = (r < N) ? r : (N - 1);   // clamp: avoids OOB, masked at store
    }
    const u16* bbase_p = Kcomb + (size_t)pbase * 512 + (size_t)l15 * 512 + kg * 8;

    // ---- first half: A = agg rows (d_out slots, u16 stride 512) ----
#pragma unroll 2
    for (int k0 = 0; k0 < 256; k0 += 32) {
        int kk = k0 + kg * 8;
        bf16x8 a[2], b[4];
#pragma unroll
        for (int f = 0; f < 2; ++f)
            a[f] = *(const bf16x8*)(agg_bf + (size_t)rowA[f] * 512 + kk);
#pragma unroll
        for (int nf = 0; nf < 4; ++nf)
            b[nf] = *(const bf16x8*)(bbase_p + (size_t)nf * 16 * 512 + k0);
#pragma unroll
        for (int f = 0; f < 2; ++f)
#pragma unroll
            for (int nf = 0; nf < 4; ++nf)
                acc[f][nf] = __builtin_amdgcn_mfma_f32_16x16x32_bf16(a[f], b[nf], acc[f][nf], 0, 0, 0);
    }
    // ---- second half: A = h rows ----
#pragma unroll 2
    for (int k0 = 256; k0 < 512; k0 += 32) {
        int kh = (k0 - 256) + kg * 8;
        bf16x8 a[2], b[4];
        if (BF) {
#pragma unroll
            for (int f = 0; f < 2; ++f)
                a[f] = *(const bf16x8*)(h_bf + (size_t)rowA[f] * 256 + kh);
        } else {
#pragma unroll
            for (int f = 0; f < 2; ++f) {
                const float* hp = h + (size_t)rowA[f] * 256 + kh;
                float4 f0 = *(const float4*)hp, f1 = *(const float4*)(hp + 4);
                u16 tmp[8] = {f2bf(f0.x), f2bf(f0.y), f2bf(f0.z), f2bf(f0.w),
                              f2bf(f1.x), f2bf(f1.y), f2bf(f1.z), f2bf(f1.w)};
                a[f] = *(const bf16x8*)tmp;
            }
        }
#pragma unroll
        for (int nf = 0; nf < 4; ++nf)
            b[nf] = *(const bf16x8*)(bbase_p + (size_t)nf * 16 * 512 + k0);
#pragma unroll
        for (int f = 0; f < 2; ++f)
#pragma unroll
            for (int nf = 0; nf < 4; ++nf)
                acc[f][nf] = __builtin_amdgcn_mfma_f32_16x16x32_bf16(a[f], b[nf], acc[f][nf], 0, 0, 0);
    }

    // ---- epilogue: y = acc + c0[p] + c1[p]*wsum[row]; coalesced-ish store ----
    float b0[4], b1[4];
#pragma unroll
    for (int nf = 0; nf < 4; ++nf) {
        int p = pbase + nf * 16 + l15;
        b0[nf] = c0[p];
        b1[nf] = c1[p];
    }
#pragma unroll
    for (int f = 0; f < 2; ++f) {
#pragma unroll
        for (int r = 0; r < 4; ++r) {
            int row = m0 + f * 16 + kg * 4 + r;
            if (row >= N) continue;
            float wsv = wsum_arr[row];
#pragma unroll
            for (int nf = 0; nf < 4; ++nf) {
                int p = pbase + nf * 16 + l15;
                dio[(size_t)row * 256 + p] = acc[f][nf][r] + b0[nf] + b1[nf] * wsv;
            }
        }
    }
}

static inline size_t align4(size_t x) { return (x + 3) & ~(size_t)3; }

extern "C" void kernel_launch(void* const* d_in, const int* in_sizes, int n_in,
                              void* d_out, int out_size, void* d_ws, size_t ws_size,
                              hipStream_t stream) {
    const float* h       = (const float*)d_in[0];
    const int*   ei      = (const int*)d_in[1];   // (2,E) row-major
    const int*   et      = (const int*)d_in[2];
    const float* rel_emb = (const float*)d_in[3];
    const float* msg_w   = (const float*)d_in[4];
    const float* msg_b   = (const float*)d_in[5];
    const float* upd_w   = (const float*)d_in[6];
    const float* upd_b   = (const float*)d_in[7];
    const float* gate_w  = (const float*)d_in[8];
    const float* gate_b  = (const float*)d_in[9];

    const int N = in_sizes[0] / 256;
    const int E = in_sizes[2];
    const int R = in_sizes[3] / 256;

    // workspace layout (u32 units); total+deg_src+deg_dst contiguous for memset
    u32* ws = (u32*)d_ws;
    size_t o = 0;
    u32* total    = ws + o; o += 4;
    u32* deg_src  = ws + o; o += align4((size_t)N);
    u32* deg_dst  = ws + o; o += align4((size_t)N);
    u32* offs     = ws + o; o += align4((size_t)N);
    u32* cursor   = ws + o; o += align4((size_t)N);
    float* wsum   = (float*)(ws + o); o += align4((size_t)N);
    float* gate   = (float*)(ws + o); o += align4((size_t)R);
    uint4* edata  = (uint4*)(ws + o); o += (size_t)4 * E;
    float* Mf     = (float*)(ws + o); o += 65536;   // 256x256 fp32
    u16* Kcomb    = (u16*)(ws + o); o += 65536;     // 256x512 bf16
    float* c0     = (float*)(ws + o); o += 256;
    float* c1     = (float*)(ws + o); o += 256;
    size_t need_base = o;
    u16* h_bf     = (u16*)(ws + o); o += (size_t)N * 128;
    u16* rel_bf   = (u16*)(ws + o); o += (size_t)R * 128;
    size_t need_bf = o;

    if (ws_size < need_base * 4) return;  // insufficient scratch -> fail loudly
    const bool use_bf = (ws_size >= need_bf * 4);

    float* out = (float*)d_out;
    u16* agg_bf = (u16*)d_out;   // bf16 rows at u16 stride 512 (half of each slot)

    // zero total + degree counters (contiguous)
    hipMemsetAsync(total, 0, (4 + 2 * align4((size_t)N)) * 4, stream);

    build_m_kernel<<<256, 256, 0, stream>>>(msg_w, Mf);
    build_comb_kernel<<<256, 256, 0, stream>>>(upd_w, upd_b, msg_b, Mf, Kcomb, c0, c1);
    gate_kernel<<<(R + 3) / 4, 256, 0, stream>>>(rel_emb, gate_w, gate_b, gate, R);
    degree_kernel<<<(E + 255) / 256, 256, 0, stream>>>(ei, E, deg_src, deg_dst);
    alloc_kernel<<<(N + 255) / 256, 256, 0, stream>>>(deg_dst, offs, cursor, total, N);
    if (use_bf) {
        tobf_kernel<<<1024, 256, 0, stream>>>(h, h_bf, N * 32);       // N*256/8
        tobf_kernel<<<64, 256, 0, stream>>>(rel_emb, rel_bf, R * 32); // R*256/8
    }
    fill_kernel<<<(E + 255) / 256, 256, 0, stream>>>(ei, et, deg_src, deg_dst, gate,
                                                     cursor, edata, E);
    const int nblk = (N + 31) / 32;
    if (use_bf) {
        agg_kernel<1><<<(N + 3) / 4, 256, 0, stream>>>(h, h_bf, rel_emb, rel_bf, offs,
                                                       deg_dst, edata, agg_bf, wsum, N);
        gemm_reg_kernel<1><<<nblk, 256, 0, stream>>>(out, agg_bf, Kcomb, h, h_bf,
                                                     wsum, c0, c1, N);
    } else {
        agg_kernel<0><<<(N + 3) / 4, 256, 0, stream>>>(h, h_bf, rel_emb, rel_bf, offs,
                                                       deg_dst, edata, agg_bf, wsum, N);
        gemm_reg_kernel<0><<<nblk, 256, 0, stream>>>(out, agg_bf, Kcomb, h, h_bf,
                                                     wsum, c0, c1, N);
    }
}

// Round 8
// 294.146 us; speedup vs baseline: 1.2150x; 1.2150x over previous
//
#include <hip/hip_runtime.h>
#include <math.h>

typedef unsigned int u32;
typedef unsigned short u16;
typedef __attribute__((ext_vector_type(8))) short bf16x8;   // 8 bf16 in 4 VGPRs
typedef __attribute__((ext_vector_type(4))) float f32x4;

#define GLOBAL_AS __attribute__((address_space(1)))
#define LDS_AS __attribute__((address_space(3)))

__device__ __forceinline__ void gload_lds16(const void* g, void* s) {
    __builtin_amdgcn_global_load_lds((const GLOBAL_AS void*)g, (LDS_AS void*)s, 16, 0, 0);
}

__device__ inline u16 f2bf(float x) {  // round-to-nearest-even
    union { float f; u32 u; } v; v.f = x;
    u32 r = v.u + 0x7FFFu + ((v.u >> 16) & 1u);
    return (u16)(r >> 16);
}
__device__ inline float4 bf4_to_f4(uint2 p) {
    float4 r;
    r.x = __uint_as_float(p.x << 16);
    r.y = __uint_as_float(p.x & 0xffff0000u);
    r.z = __uint_as_float(p.y << 16);
    r.w = __uint_as_float(p.y & 0xffff0000u);
    return r;
}

// ---------------------------------------------------------------------------
// Clifford GNN message passing, fully linearized:
//   agg[n] = sum_e w_e*(h[src] .* r[rel]),  w_e = gate(rel)*norm(e)
//   out    = (Ku.Km).agg + Ku.h + ws*(Ku.msg_b) + upd_b
// One K=512 MFMA GEMM on x=[agg_row | h_row], Kcomb=[Ku.Km|Ku] (rows
// output-permuted for coalesced stores, replicated 8x so each XCD's L2
// keeps a hot copy). A-tile staged into LDS once per block via async
// global_load_lds (pre-swizzled per-lane sources); B read from L2 replica.
// ---------------------------------------------------------------------------

// Mf[k*256+i] = M[k][i] fp32 (message Clifford matrix, row k = output idx)
__global__ void build_m_kernel(const float* __restrict__ msg_w, float* __restrict__ Mf) {
    const int   s_tab[16] = {0,1,2,3, 1,0,3,2, 2,3,0,1, 3,2,1,0};
    const float g_tab[16] = {1.f,1.f,1.f,-1.f, 1.f,1.f,-1.f,1.f,
                             1.f,1.f,1.f,-1.f, 1.f,1.f,1.f,1.f};
    int idx = blockIdx.x * 256 + threadIdx.x;   // idx = k*256 + i
    int k = idx >> 8, i = idx & 255;
    int ob = k >> 6, oc = k & 63, ib = i >> 6, ic = i & 63;
    int t = ob * 4 + ib;
    Mf[idx] = g_tab[t] * msg_w[s_tab[t] * 4096 + oc * 64 + ic];
}

// Block p builds output-permuted row p of Kcomb (512 wide bf16, 8 replicas)
// + c0[p], c1[p].  j = (p&3)*64 + (p>>2);
// Kcomb[p][0:256] = (U.M)[j][:], Kcomb[p][256:512] = U[j][:]
__global__ __launch_bounds__(256) void build_comb_kernel(
    const float* __restrict__ upd_w, const float* __restrict__ upd_b,
    const float* __restrict__ msg_b, const float* __restrict__ Mf,
    u16* __restrict__ Kcomb, float* __restrict__ c0, float* __restrict__ c1) {
    const int   s_tab[16] = {0,1,2,3, 1,0,3,2, 2,3,0,1, 3,2,1,0};
    const float g_tab[16] = {1.f,1.f,1.f,-1.f, 1.f,1.f,-1.f,1.f,
                             1.f,1.f,1.f,-1.f, 1.f,1.f,1.f,1.f};
    __shared__ float U_s[256];
    __shared__ float wred[4];
    int p = blockIdx.x;
    int j = (p & 3) * 64 + (p >> 2);
    int tid = threadIdx.x;
    {
        int ob = j >> 6, oc = j & 63, ib = tid >> 6, ic = tid & 63;
        int t = ob * 4 + ib;
        U_s[tid] = g_tab[t] * upd_w[s_tab[t] * 4096 + oc * 64 + ic];
    }
    __syncthreads();
    float acc = 0.f;
#pragma unroll 8
    for (int k = 0; k < 256; ++k) acc += U_s[k] * Mf[k * 256 + tid];
    u16 vA = f2bf(acc);
    u16 vU = f2bf(U_s[tid]);
#pragma unroll
    for (int r = 0; r < 8; ++r) {        // 8 replicas (one per XCD's L2)
        Kcomb[(size_t)r * 131072 + (size_t)p * 512 + tid] = vA;
        Kcomb[(size_t)r * 131072 + (size_t)p * 512 + 256 + tid] = vU;
    }
    float part = U_s[tid] * msg_b[tid];
    int lane = tid & 63, wv = tid >> 6;
#pragma unroll
    for (int d = 32; d > 0; d >>= 1) part += __shfl_down(part, d);
    if (lane == 0) wred[wv] = part;
    __syncthreads();
    if (tid == 0) { c1[p] = wred[0] + wred[1] + wred[2] + wred[3]; c0[p] = upd_b[j]; }
}

// gate[r] = sigmoid( sum_j rel_emb[r, j] * gate_w[(j&63)*4 + (j>>6)] + gate_b )
__global__ void gate_kernel(const float* __restrict__ rel_emb,
                            const float* __restrict__ gate_w,
                            const float* __restrict__ gate_b,
                            float* __restrict__ gate, int R) {
    int wv = threadIdx.x >> 6, lane = threadIdx.x & 63;
    int r = blockIdx.x * 4 + wv;
    if (r >= R) return;
    float4 rv = *(const float4*)(rel_emb + (size_t)r * 256 + lane * 4);
    float s = 0.f;
    float rvv[4] = {rv.x, rv.y, rv.z, rv.w};
#pragma unroll
    for (int c = 0; c < 4; ++c) {
        int j = lane * 4 + c;
        s += rvv[c] * gate_w[(j & 63) * 4 + (j >> 6)];
    }
#pragma unroll
    for (int d = 32; d > 0; d >>= 1) s += __shfl_down(s, d);
    if (lane == 0) gate[r] = 1.0f / (1.0f + expf(-(s + gate_b[0])));
}

__global__ void degree_kernel(const int* __restrict__ ei, int E,
                              u32* __restrict__ deg_src, u32* __restrict__ deg_dst) {
    int e = blockIdx.x * 256 + threadIdx.x;
    if (e >= E) return;
    atomicAdd(&deg_src[ei[e]], 1u);
    atomicAdd(&deg_dst[ei[E + e]], 1u);
}

// Parallel bucket allocator (order irrelevant, only disjointness matters).
__global__ void alloc_kernel(const u32* __restrict__ deg, u32* __restrict__ offs,
                             u32* __restrict__ cursor, u32* __restrict__ total, int N) {
    __shared__ u32 wt[4];
    __shared__ u32 bbase;
    int tid = threadIdx.x, lane = tid & 63, wv = tid >> 6;
    int i = blockIdx.x * 256 + tid;
    u32 d = (i < N) ? deg[i] : 0u;
    u32 sc = d;
#pragma unroll
    for (int s = 1; s < 64; s <<= 1) { u32 o = __shfl_up(sc, s); if (lane >= s) sc += o; }
    if (lane == 63) wt[wv] = sc;
    __syncthreads();
    if (tid == 0) bbase = atomicAdd(total, wt[0] + wt[1] + wt[2] + wt[3]);
    __syncthreads();
    u32 wpre = 0;
    for (int w = 0; w < wv; ++w) wpre += wt[w];
    u32 off = bbase + wpre + sc - d;
    if (i < N) { offs[i] = off; cursor[i] = off; }
}

// Bucket-fill, packed metadata: edata[pos] = {src, rel, w_bits, 0}.
__global__ void fill_kernel(const int* __restrict__ ei, const int* __restrict__ et,
                            const u32* __restrict__ deg_src,
                            const u32* __restrict__ deg_dst,
                            const float* __restrict__ gate,
                            u32* __restrict__ cursor, uint4* __restrict__ edata, int E) {
    int e = blockIdx.x * 256 + threadIdx.x;
    if (e >= E) return;
    int src = ei[e];
    int dst = ei[E + e];
    int rel = et[e];
    float w = gate[rel] * rsqrtf(fmaxf((float)deg_src[src] * (float)deg_dst[dst], 1.0f));
    u32 pos = atomicAdd(&cursor[dst], 1u);
    edata[pos] = make_uint4((u32)src, (u32)rel, __float_as_uint(w), 0u);
}

// fp32 -> bf16 bulk convert (8 elems/thread, grid-stride).
__global__ void tobf_kernel(const float* __restrict__ src, u16* __restrict__ dst, int n8) {
    for (int i = blockIdx.x * 256 + threadIdx.x; i < n8; i += gridDim.x * 256) {
        const float* p = src + (size_t)i * 8;
        float4 a = *(const float4*)(p);
        float4 b = *(const float4*)(p + 4);
        u16 tmp[8] = {f2bf(a.x), f2bf(a.y), f2bf(a.z), f2bf(a.w),
                      f2bf(b.x), f2bf(b.y), f2bf(b.z), f2bf(b.w)};
        *(uint4*)(dst + (size_t)i * 8) = *(const uint4*)tmp;
    }
}

// One wave per node: agg row (bf16) into first 512B of d_out's 1KB slot + wsum.
template <int BF>
__global__ __launch_bounds__(256) void agg_kernel(
    const float* __restrict__ h, const u16* __restrict__ h_bf,
    const float* __restrict__ rel_emb, const u16* __restrict__ rel_bf,
    const u32* __restrict__ offs, const u32* __restrict__ deg_dst,
    const uint4* __restrict__ edata,
    u16* __restrict__ agg_bf, float* __restrict__ wsum_arr, int N) {
    int wv = threadIdx.x >> 6, lane = threadIdx.x & 63;
    int n = blockIdx.x * 4 + wv;
    if (n >= N) return;
    u32 off = offs[n];
    u32 dd = deg_dst[n];
    float4 acc = make_float4(0.f, 0.f, 0.f, 0.f);
    float wsum = 0.f;
    u32 e = 0;
    for (; e + 4 <= dd; e += 4) {
        uint4 d[4];
        float4 hv[4], rv[4];
#pragma unroll
        for (int q = 0; q < 4; ++q) d[q] = edata[off + e + q];
#pragma unroll
        for (int q = 0; q < 4; ++q) {
            if (BF) {
                hv[q] = bf4_to_f4(*(const uint2*)(h_bf + (size_t)d[q].x * 256 + lane * 4));
                rv[q] = bf4_to_f4(*(const uint2*)(rel_bf + (size_t)d[q].y * 256 + lane * 4));
            } else {
                hv[q] = *(const float4*)(h + (size_t)d[q].x * 256 + lane * 4);
                rv[q] = *(const float4*)(rel_emb + (size_t)d[q].y * 256 + lane * 4);
            }
        }
#pragma unroll
        for (int q = 0; q < 4; ++q) {
            float w = __uint_as_float(d[q].z);
            acc.x += w * hv[q].x * rv[q].x;
            acc.y += w * hv[q].y * rv[q].y;
            acc.z += w * hv[q].z * rv[q].z;
            acc.w += w * hv[q].w * rv[q].w;
            wsum += w;
        }
    }
    for (; e < dd; ++e) {
        uint4 d0 = edata[off + e];
        float w0 = __uint_as_float(d0.z);
        float4 h0, r0;
        if (BF) {
            h0 = bf4_to_f4(*(const uint2*)(h_bf + (size_t)d0.x * 256 + lane * 4));
            r0 = bf4_to_f4(*(const uint2*)(rel_bf + (size_t)d0.y * 256 + lane * 4));
        } else {
            h0 = *(const float4*)(h + (size_t)d0.x * 256 + lane * 4);
            r0 = *(const float4*)(rel_emb + (size_t)d0.y * 256 + lane * 4);
        }
        acc.x += w0 * h0.x * r0.x;
        acc.y += w0 * h0.y * r0.y;
        acc.z += w0 * h0.z * r0.z;
        acc.w += w0 * h0.w * r0.w;
        wsum += w0;
    }
    u32 lo = (u32)f2bf(acc.x) | ((u32)f2bf(acc.y) << 16);
    u32 hi = (u32)f2bf(acc.z) | ((u32)f2bf(acc.w) << 16);
    *(uint2*)(agg_bf + (size_t)n * 512 + lane * 4) = make_uint2(lo, hi);
    if (lane == 0) wsum_arr[n] = wsum;
}

// LDS-staged K=512 GEMM. Block = 64 rows x 256 cols; 4 waves, each 64x64
// (acc 4x4 frags). x=[agg|h] staged async into swizzled LDS (64KB) via
// global_load_lds: dest linear, per-lane SOURCE pre-swizzled (k ^ ((m&7)<<3)),
// lanes 0-31 pull agg (d_out slot), lanes 32-63 pull h_bf. One barrier.
// K-loop: 4 ds_read_b128(A, conflict-free) + 4 global(B, per-XCD L2 replica)
// + 16 MFMA per step.  out[row][p] = acc + c0[p] + c1[p]*wsum[row].
__global__ __launch_bounds__(256, 2) void gemm_lds_kernel(
    float* __restrict__ dio, const u16* __restrict__ agg_bf,
    const u16* __restrict__ Kcomb, const u16* __restrict__ h_bf,
    const float* __restrict__ wsum_arr,
    const float* __restrict__ c0, const float* __restrict__ c1, int N) {
    __shared__ __align__(16) u16 xs[64 * 512];   // 64 KiB
    const int lane = threadIdx.x & 63;
    const int wv = threadIdx.x >> 6;      // wave owns output cols [wv*64, +64)
    const int l15 = lane & 15;
    const int kg = lane >> 4;             // k-group 0..3
    const int m0 = blockIdx.x * 64;
    const int pbase = wv * 64;
    const u16* Kr = Kcomb + (size_t)(blockIdx.x & 7) * 131072;  // XCD replica

    // ---- async stage x=[agg|h] rows -> swizzled LDS (1 row / issue) ----
    {
        int j0 = lane * 8;                       // dest u16 offset in row
#pragma unroll
        for (int i = 0; i < 16; ++i) {
            int m = i * 4 + wv;                  // 0..63
            int row = m0 + m;
            if (row >= N) row = N - 1;           // clamp; masked at store
            int ks = j0 ^ ((m & 7) << 3);        // pre-swizzled source k
            const u16* src = (j0 < 256)
                ? agg_bf + (size_t)row * 512 + ks
                : h_bf + (size_t)row * 256 + (ks - 256);
            gload_lds16(src, &xs[m * 512]);
        }
    }
    __syncthreads();   // drains global_load_lds; also fences in-place d_out use

    f32x4 acc[4][4];
#pragma unroll
    for (int f = 0; f < 4; ++f)
#pragma unroll
        for (int nf = 0; nf < 4; ++nf) acc[f][nf] = (f32x4)(0.f);

    const int swz = (l15 & 7) << 3;
#pragma unroll 4
    for (int k0 = 0; k0 < 512; k0 += 32) {
        int kk = k0 + kg * 8;
        bf16x8 a[4], b[4];
#pragma unroll
        for (int f = 0; f < 4; ++f)
            a[f] = *(const bf16x8*)&xs[(f * 16 + l15) * 512 + (kk ^ swz)];
#pragma unroll
        for (int nf = 0; nf < 4; ++nf)
            b[nf] = *(const bf16x8*)(Kr + (size_t)(pbase + nf * 16 + l15) * 512 + kk);
#pragma unroll
        for (int f = 0; f < 4; ++f)
#pragma unroll
            for (int nf = 0; nf < 4; ++nf)
                acc[f][nf] = __builtin_amdgcn_mfma_f32_16x16x32_bf16(a[f], b[nf], acc[f][nf], 0, 0, 0);
    }

    // ---- epilogue: y = acc + c0[p] + c1[p]*wsum[row] ----
    float b0[4], b1[4];
#pragma unroll
    for (int nf = 0; nf < 4; ++nf) {
        int p = pbase + nf * 16 + l15;
        b0[nf] = c0[p];
        b1[nf] = c1[p];
    }
#pragma unroll
    for (int f = 0; f < 4; ++f) {
#pragma unroll
        for (int r = 0; r < 4; ++r) {
            int row = m0 + f * 16 + kg * 4 + r;
            if (row >= N) continue;
            float wsv = wsum_arr[row];
#pragma unroll
            for (int nf = 0; nf < 4; ++nf) {
                int p = pbase + nf * 16 + l15;
                dio[(size_t)row * 256 + p] = acc[f][nf][r] + b0[nf] + b1[nf] * wsv;
            }
        }
    }
}

// Fallback (no bf16 workspace): register GEMM, barrier before epilogue
// (fixes the r6/r7 latent wave race on in-place agg overwrite).
__global__ __launch_bounds__(256, 4) void gemm_reg_kernel(
    float* __restrict__ dio, const u16* __restrict__ agg_bf,
    const u16* __restrict__ Kcomb,
    const float* __restrict__ h,
    const float* __restrict__ wsum_arr,
    const float* __restrict__ c0, const float* __restrict__ c1, int N) {
    const int lane = threadIdx.x & 63;
    const int wv = threadIdx.x >> 6;
    const int l15 = lane & 15;
    const int kg = lane >> 4;
    const int m0 = blockIdx.x * 32;
    const int pbase = wv * 64;

    f32x4 acc[2][4];
#pragma unroll
    for (int f = 0; f < 2; ++f)
#pragma unroll
        for (int nf = 0; nf < 4; ++nf) acc[f][nf] = (f32x4)(0.f);

    int rowA[2];
#pragma unroll
    for (int f = 0; f < 2; ++f) {
        int r = m0 + f * 16 + l15;
        rowA[f] = (r < N) ? r : (N - 1);
    }
    const u16* Kr = Kcomb + (size_t)(blockIdx.x & 7) * 131072;
    const u16* bbase_p = Kr + (size_t)pbase * 512 + (size_t)l15 * 512 + kg * 8;

#pragma unroll 2
    for (int k0 = 0; k0 < 256; k0 += 32) {
        int kk = k0 + kg * 8;
        bf16x8 a[2], b[4];
#pragma unroll
        for (int f = 0; f < 2; ++f)
            a[f] = *(const bf16x8*)(agg_bf + (size_t)rowA[f] * 512 + kk);
#pragma unroll
        for (int nf = 0; nf < 4; ++nf)
            b[nf] = *(const bf16x8*)(bbase_p + (size_t)nf * 16 * 512 + k0);
#pragma unroll
        for (int f = 0; f < 2; ++f)
#pragma unroll
            for (int nf = 0; nf < 4; ++nf)
                acc[f][nf] = __builtin_amdgcn_mfma_f32_16x16x32_bf16(a[f], b[nf], acc[f][nf], 0, 0, 0);
    }
#pragma unroll 2
    for (int k0 = 256; k0 < 512; k0 += 32) {
        int kh = (k0 - 256) + kg * 8;
        bf16x8 a[2], b[4];
#pragma unroll
        for (int f = 0; f < 2; ++f) {
            const float* hp = h + (size_t)rowA[f] * 256 + kh;
            float4 f0 = *(const float4*)hp, f1 = *(const float4*)(hp + 4);
            u16 tmp[8] = {f2bf(f0.x), f2bf(f0.y), f2bf(f0.z), f2bf(f0.w),
                          f2bf(f1.x), f2bf(f1.y), f2bf(f1.z), f2bf(f1.w)};
            a[f] = *(const bf16x8*)tmp;
        }
#pragma unroll
        for (int nf = 0; nf < 4; ++nf)
            b[nf] = *(const bf16x8*)(bbase_p + (size_t)nf * 16 * 512 + k0);
#pragma unroll
        for (int f = 0; f < 2; ++f)
#pragma unroll
            for (int nf = 0; nf < 4; ++nf)
                acc[f][nf] = __builtin_amdgcn_mfma_f32_16x16x32_bf16(a[f], b[nf], acc[f][nf], 0, 0, 0);
    }

    __syncthreads();   // all waves done reading agg before in-place overwrite

    float b0[4], b1[4];
#pragma unroll
    for (int nf = 0; nf < 4; ++nf) {
        int p = pbase + nf * 16 + l15;
        b0[nf] = c0[p];
        b1[nf] = c1[p];
    }
#pragma unroll
    for (int f = 0; f < 2; ++f) {
#pragma unroll
        for (int r = 0; r < 4; ++r) {
            int row = m0 + f * 16 + kg * 4 + r;
            if (row >= N) continue;
            float wsv = wsum_arr[row];
#pragma unroll
            for (int nf = 0; nf < 4; ++nf) {
                int p = pbase + nf * 16 + l15;
                dio[(size_t)row * 256 + p] = acc[f][nf][r] + b0[nf] + b1[nf] * wsv;
            }
        }
    }
}

static inline size_t align4(size_t x) { return (x + 3) & ~(size_t)3; }

extern "C" void kernel_launch(void* const* d_in, const int* in_sizes, int n_in,
                              void* d_out, int out_size, void* d_ws, size_t ws_size,
                              hipStream_t stream) {
    const float* h       = (const float*)d_in[0];
    const int*   ei      = (const int*)d_in[1];   // (2,E) row-major
    const int*   et      = (const int*)d_in[2];
    const float* rel_emb = (const float*)d_in[3];
    const float* msg_w   = (const float*)d_in[4];
    const float* msg_b   = (const float*)d_in[5];
    const float* upd_w   = (const float*)d_in[6];
    const float* upd_b   = (const float*)d_in[7];
    const float* gate_w  = (const float*)d_in[8];
    const float* gate_b  = (const float*)d_in[9];

    const int N = in_sizes[0] / 256;
    const int E = in_sizes[2];
    const int R = in_sizes[3] / 256;

    // workspace layout (u32 units); total+deg_src+deg_dst contiguous for memset
    u32* ws = (u32*)d_ws;
    size_t o = 0;
    u32* total    = ws + o; o += 4;
    u32* deg_src  = ws + o; o += align4((size_t)N);
    u32* deg_dst  = ws + o; o += align4((size_t)N);
    u32* offs     = ws + o; o += align4((size_t)N);
    u32* cursor   = ws + o; o += align4((size_t)N);
    float* wsum   = (float*)(ws + o); o += align4((size_t)N);
    float* gate   = (float*)(ws + o); o += align4((size_t)R);
    uint4* edata  = (uint4*)(ws + o); o += (size_t)4 * E;
    float* Mf     = (float*)(ws + o); o += 65536;   // 256x256 fp32
    u16* Kcomb    = (u16*)(ws + o); o += 524288;    // 8 x (256x512 bf16) replicas
    float* c0     = (float*)(ws + o); o += 256;
    float* c1     = (float*)(ws + o); o += 256;
    size_t need_base = o;
    u16* h_bf     = (u16*)(ws + o); o += (size_t)N * 128;
    u16* rel_bf   = (u16*)(ws + o); o += (size_t)R * 128;
    size_t need_bf = o;

    if (ws_size < need_base * 4) return;  // insufficient scratch -> fail loudly
    const bool use_bf = (ws_size >= need_bf * 4);

    float* out = (float*)d_out;
    u16* agg_bf = (u16*)d_out;   // bf16 rows at u16 stride 512 (half of each slot)

    // zero total + degree counters (contiguous)
    hipMemsetAsync(total, 0, (4 + 2 * align4((size_t)N)) * 4, stream);

    build_m_kernel<<<256, 256, 0, stream>>>(msg_w, Mf);
    build_comb_kernel<<<256, 256, 0, stream>>>(upd_w, upd_b, msg_b, Mf, Kcomb, c0, c1);
    gate_kernel<<<(R + 3) / 4, 256, 0, stream>>>(rel_emb, gate_w, gate_b, gate, R);
    degree_kernel<<<(E + 255) / 256, 256, 0, stream>>>(ei, E, deg_src, deg_dst);
    alloc_kernel<<<(N + 255) / 256, 256, 0, stream>>>(deg_dst, offs, cursor, total, N);
    if (use_bf) {
        tobf_kernel<<<1024, 256, 0, stream>>>(h, h_bf, N * 32);       // N*256/8
        tobf_kernel<<<64, 256, 0, stream>>>(rel_emb, rel_bf, R * 32); // R*256/8
    }
    fill_kernel<<<(E + 255) / 256, 256, 0, stream>>>(ei, et, deg_src, deg_dst, gate,
                                                     cursor, edata, E);
    if (use_bf) {
        agg_kernel<1><<<(N + 3) / 4, 256, 0, stream>>>(h, h_bf, rel_emb, rel_bf, offs,
                                                       deg_dst, edata, agg_bf, wsum, N);
        gemm_lds_kernel<<<(N + 63) / 64, 256, 0, stream>>>(out, agg_bf, Kcomb, h_bf,
                                                           wsum, c0, c1, N);
    } else {
        agg_kernel<0><<<(N + 3) / 4, 256, 0, stream>>>(h, h_bf, rel_emb, rel_bf, offs,
                                                       deg_dst, edata, agg_bf, wsum, N);
        gemm_reg_kernel<<<(N + 31) / 32, 256, 0, stream>>>(out, agg_bf, Kcomb, h,
                                                           wsum, c0, c1, N);
    }
}

// Round 9
// 258.383 us; speedup vs baseline: 1.3832x; 1.1384x over previous
//
#include <hip/hip_runtime.h>
#include <math.h>

typedef unsigned int u32;
typedef unsigned short u16;
typedef __attribute__((ext_vector_type(8))) short bf16x8;   // 8 bf16 in 4 VGPRs
typedef __attribute__((ext_vector_type(4))) float f32x4;

#define GLOBAL_AS __attribute__((address_space(1)))
#define LDS_AS __attribute__((address_space(3)))

__device__ __forceinline__ void gload_lds16(const void* g, void* s) {
    __builtin_amdgcn_global_load_lds((const GLOBAL_AS void*)g, (LDS_AS void*)s, 16, 0, 0);
}

__device__ inline u16 f2bf(float x) {  // round-to-nearest-even
    union { float f; u32 u; } v; v.f = x;
    u32 r = v.u + 0x7FFFu + ((v.u >> 16) & 1u);
    return (u16)(r >> 16);
}
__device__ inline float4 bf4_to_f4(uint2 p) {
    float4 r;
    r.x = __uint_as_float(p.x << 16);
    r.y = __uint_as_float(p.x & 0xffff0000u);
    r.z = __uint_as_float(p.y << 16);
    r.w = __uint_as_float(p.y & 0xffff0000u);
    return r;
}

// ---------------------------------------------------------------------------
// Clifford GNN message passing, fully linearized:
//   agg[n] = sum_e w_e*(h[src] .* r[rel]),  w_e = gate(rel)*norm(e)
//   out    = (Ku.Km).agg + Ku.h + ws*(Ku.msg_b) + upd_b
// One K=512 MFMA GEMM on x=[agg_row | h_row]. Kcomb=[Ku.Km|Ku] is stored
// FRAGMENT-PACKED (each 16x32 MFMA B-fragment = 64 lanes x 16B contiguous ->
// one fully-coalesced 1KB load) and replicated 8x (one copy hot per XCD L2).
// A staged into 32KB LDS per 32-row block via async global_load_lds
// (pre-swizzled per-lane sources); 4 blocks/CU for latency overlap.
// ---------------------------------------------------------------------------

// Mf[k*256+i] = M[k][i] fp32 (message Clifford matrix, row k = output idx)
__global__ void build_m_kernel(const float* __restrict__ msg_w, float* __restrict__ Mf) {
    const int   s_tab[16] = {0,1,2,3, 1,0,3,2, 2,3,0,1, 3,2,1,0};
    const float g_tab[16] = {1.f,1.f,1.f,-1.f, 1.f,1.f,-1.f,1.f,
                             1.f,1.f,1.f,-1.f, 1.f,1.f,1.f,1.f};
    int idx = blockIdx.x * 256 + threadIdx.x;   // idx = k*256 + i
    int k = idx >> 8, i = idx & 255;
    int ob = k >> 6, oc = k & 63, ib = i >> 6, ic = i & 63;
    int t = ob * 4 + ib;
    Mf[idx] = g_tab[t] * msg_w[s_tab[t] * 4096 + oc * 64 + ic];
}

// Block p builds output-permuted row p of Kcomb in FRAGMENT-PACKED layout,
// 8 replicas, + c0[p], c1[p].   j = (p&3)*64 + (p>>2)
// Row p, col k (k<256: (U.M)[j][k]; k>=256: U[j][k-256]).
// Fragment address (u16): frag_id = (p>>4)*16 + (k>>5); lane = ((k>>3)&3)*16 + (p&15);
//   addr = frag_id*512 + lane*8 + (k&7)
__global__ __launch_bounds__(256) void build_comb_kernel(
    const float* __restrict__ upd_w, const float* __restrict__ upd_b,
    const float* __restrict__ msg_b, const float* __restrict__ Mf,
    u16* __restrict__ Kcomb, float* __restrict__ c0, float* __restrict__ c1) {
    const int   s_tab[16] = {0,1,2,3, 1,0,3,2, 2,3,0,1, 3,2,1,0};
    const float g_tab[16] = {1.f,1.f,1.f,-1.f, 1.f,1.f,-1.f,1.f,
                             1.f,1.f,1.f,-1.f, 1.f,1.f,1.f,1.f};
    __shared__ float U_s[256];
    __shared__ float wred[4];
    int p = blockIdx.x;
    int j = (p & 3) * 64 + (p >> 2);
    int tid = threadIdx.x;                 // tid = k in 0..255
    {
        int ob = j >> 6, oc = j & 63, ib = tid >> 6, ic = tid & 63;
        int t = ob * 4 + ib;
        U_s[tid] = g_tab[t] * upd_w[s_tab[t] * 4096 + oc * 64 + ic];
    }
    __syncthreads();
    float acc = 0.f;
#pragma unroll 8
    for (int k = 0; k < 256; ++k) acc += U_s[k] * Mf[k * 256 + tid];
    u16 vA = f2bf(acc);          // element (p, k=tid)
    u16 vU = f2bf(U_s[tid]);     // element (p, k=tid+256)
    int pt = p >> 4, l15 = p & 15;
    int kgA = (tid >> 3) & 3, elA = tid & 7;
    size_t addrA = (size_t)(pt * 16 + (tid >> 5)) * 512 + (kgA * 16 + l15) * 8 + elA;
    int ku = tid + 256;
    size_t addrU = (size_t)(pt * 16 + (ku >> 5)) * 512 + (kgA * 16 + l15) * 8 + elA;
#pragma unroll
    for (int r = 0; r < 8; ++r) {        // 8 replicas (one per XCD's L2)
        Kcomb[(size_t)r * 131072 + addrA] = vA;
        Kcomb[(size_t)r * 131072 + addrU] = vU;
    }
    float part = U_s[tid] * msg_b[tid];
    int lane = tid & 63, wv = tid >> 6;
#pragma unroll
    for (int d = 32; d > 0; d >>= 1) part += __shfl_down(part, d);
    if (lane == 0) wred[wv] = part;
    __syncthreads();
    if (tid == 0) { c1[p] = wred[0] + wred[1] + wred[2] + wred[3]; c0[p] = upd_b[j]; }
}

// gate[r] = sigmoid( sum_j rel_emb[r, j] * gate_w[(j&63)*4 + (j>>6)] + gate_b )
__global__ void gate_kernel(const float* __restrict__ rel_emb,
                            const float* __restrict__ gate_w,
                            const float* __restrict__ gate_b,
                            float* __restrict__ gate, int R) {
    int wv = threadIdx.x >> 6, lane = threadIdx.x & 63;
    int r = blockIdx.x * 4 + wv;
    if (r >= R) return;
    float4 rv = *(const float4*)(rel_emb + (size_t)r * 256 + lane * 4);
    float s = 0.f;
    float rvv[4] = {rv.x, rv.y, rv.z, rv.w};
#pragma unroll
    for (int c = 0; c < 4; ++c) {
        int j = lane * 4 + c;
        s += rvv[c] * gate_w[(j & 63) * 4 + (j >> 6)];
    }
#pragma unroll
    for (int d = 32; d > 0; d >>= 1) s += __shfl_down(s, d);
    if (lane == 0) gate[r] = 1.0f / (1.0f + expf(-(s + gate_b[0])));
}

__global__ void degree_kernel(const int* __restrict__ ei, int E,
                              u32* __restrict__ deg_src, u32* __restrict__ deg_dst) {
    int e = blockIdx.x * 256 + threadIdx.x;
    if (e >= E) return;
    atomicAdd(&deg_src[ei[e]], 1u);
    atomicAdd(&deg_dst[ei[E + e]], 1u);
}

// Parallel bucket allocator (order irrelevant, only disjointness matters).
__global__ void alloc_kernel(const u32* __restrict__ deg, u32* __restrict__ offs,
                             u32* __restrict__ cursor, u32* __restrict__ total, int N) {
    __shared__ u32 wt[4];
    __shared__ u32 bbase;
    int tid = threadIdx.x, lane = tid & 63, wv = tid >> 6;
    int i = blockIdx.x * 256 + tid;
    u32 d = (i < N) ? deg[i] : 0u;
    u32 sc = d;
#pragma unroll
    for (int s = 1; s < 64; s <<= 1) { u32 o = __shfl_up(sc, s); if (lane >= s) sc += o; }
    if (lane == 63) wt[wv] = sc;
    __syncthreads();
    if (tid == 0) bbase = atomicAdd(total, wt[0] + wt[1] + wt[2] + wt[3]);
    __syncthreads();
    u32 wpre = 0;
    for (int w = 0; w < wv; ++w) wpre += wt[w];
    u32 off = bbase + wpre + sc - d;
    if (i < N) { offs[i] = off; cursor[i] = off; }
}

// Bucket-fill, packed metadata: edata[pos] = {src | rel<<18, w_bits}  (8B/edge).
__global__ void fill_kernel(const int* __restrict__ ei, const int* __restrict__ et,
                            const u32* __restrict__ deg_src,
                            const u32* __restrict__ deg_dst,
                            const float* __restrict__ gate,
                            u32* __restrict__ cursor, uint2* __restrict__ edata, int E) {
    int e = blockIdx.x * 256 + threadIdx.x;
    if (e >= E) return;
    int src = ei[e];
    int dst = ei[E + e];
    int rel = et[e];
    float w = gate[rel] * rsqrtf(fmaxf((float)deg_src[src] * (float)deg_dst[dst], 1.0f));
    u32 pos = atomicAdd(&cursor[dst], 1u);
    edata[pos] = make_uint2((u32)src | ((u32)rel << 18), __float_as_uint(w));
}

// fp32 -> bf16 bulk convert (8 elems/thread, grid-stride).
__global__ void tobf_kernel(const float* __restrict__ src, u16* __restrict__ dst, int n8) {
    for (int i = blockIdx.x * 256 + threadIdx.x; i < n8; i += gridDim.x * 256) {
        const float* p = src + (size_t)i * 8;
        float4 a = *(const float4*)(p);
        float4 b = *(const float4*)(p + 4);
        u16 tmp[8] = {f2bf(a.x), f2bf(a.y), f2bf(a.z), f2bf(a.w),
                      f2bf(b.x), f2bf(b.y), f2bf(b.z), f2bf(b.w)};
        *(uint4*)(dst + (size_t)i * 8) = *(const uint4*)tmp;
    }
}

// One wave per node: agg row (bf16) into first 512B of d_out's 1KB slot + wsum.
template <int BF>
__global__ __launch_bounds__(256) void agg_kernel(
    const float* __restrict__ h, const u16* __restrict__ h_bf,
    const float* __restrict__ rel_emb, const u16* __restrict__ rel_bf,
    const u32* __restrict__ offs, const u32* __restrict__ deg_dst,
    const uint2* __restrict__ edata,
    u16* __restrict__ agg_bf, float* __restrict__ wsum_arr, int N) {
    int wv = threadIdx.x >> 6, lane = threadIdx.x & 63;
    int n = blockIdx.x * 4 + wv;
    if (n >= N) return;
    u32 off = offs[n];
    u32 dd = deg_dst[n];
    float4 acc = make_float4(0.f, 0.f, 0.f, 0.f);
    float wsum = 0.f;
    u32 e = 0;
    for (; e + 4 <= dd; e += 4) {
        uint2 d[4];
        float4 hv[4], rv[4];
#pragma unroll
        for (int q = 0; q < 4; ++q) d[q] = edata[off + e + q];
#pragma unroll
        for (int q = 0; q < 4; ++q) {
            u32 src = d[q].x & 0x3FFFFu, rel = d[q].x >> 18;
            if (BF) {
                hv[q] = bf4_to_f4(*(const uint2*)(h_bf + (size_t)src * 256 + lane * 4));
                rv[q] = bf4_to_f4(*(const uint2*)(rel_bf + (size_t)rel * 256 + lane * 4));
            } else {
                hv[q] = *(const float4*)(h + (size_t)src * 256 + lane * 4);
                rv[q] = *(const float4*)(rel_emb + (size_t)rel * 256 + lane * 4);
            }
        }
#pragma unroll
        for (int q = 0; q < 4; ++q) {
            float w = __uint_as_float(d[q].y);
            acc.x += w * hv[q].x * rv[q].x;
            acc.y += w * hv[q].y * rv[q].y;
            acc.z += w * hv[q].z * rv[q].z;
            acc.w += w * hv[q].w * rv[q].w;
            wsum += w;
        }
    }
    for (; e < dd; ++e) {
        uint2 d0 = edata[off + e];
        u32 src = d0.x & 0x3FFFFu, rel = d0.x >> 18;
        float w0 = __uint_as_float(d0.y);
        float4 h0, r0;
        if (BF) {
            h0 = bf4_to_f4(*(const uint2*)(h_bf + (size_t)src * 256 + lane * 4));
            r0 = bf4_to_f4(*(const uint2*)(rel_bf + (size_t)rel * 256 + lane * 4));
        } else {
            h0 = *(const float4*)(h + (size_t)src * 256 + lane * 4);
            r0 = *(const float4*)(rel_emb + (size_t)rel * 256 + lane * 4);
        }
        acc.x += w0 * h0.x * r0.x;
        acc.y += w0 * h0.y * r0.y;
        acc.z += w0 * h0.z * r0.z;
        acc.w += w0 * h0.w * r0.w;
        wsum += w0;
    }
    u32 lo = (u32)f2bf(acc.x) | ((u32)f2bf(acc.y) << 16);
    u32 hi = (u32)f2bf(acc.z) | ((u32)f2bf(acc.w) << 16);
    *(uint2*)(agg_bf + (size_t)n * 512 + lane * 4) = make_uint2(lo, hi);
    if (lane == 0) wsum_arr[n] = wsum;
}

// LDS-staged K=512 GEMM. Block = 32 rows x 256 cols; 4 waves, each 32x64
// (acc 2x4 frags, ~90 regs -> 4 waves/SIMD; 32KB LDS -> 4 blocks/CU).
// x=[agg|h] staged async into swizzled LDS via global_load_lds (dest linear,
// per-lane SOURCE pre-swizzled). B = fragment-packed Kcomb: each load is
// 64 lanes x 16B contiguous (1KB coalesced burst) from the XCD-local replica.
// out[row][p] = acc + c0[p] + c1[p]*wsum[row].
__global__ __launch_bounds__(256, 4) void gemm_lds_kernel(
    float* __restrict__ dio, const u16* __restrict__ agg_bf,
    const u16* __restrict__ Kcomb, const u16* __restrict__ h_bf,
    const float* __restrict__ wsum_arr,
    const float* __restrict__ c0, const float* __restrict__ c1, int N) {
    __shared__ __align__(16) u16 xs[32 * 512];   // 32 KiB
    const int lane = threadIdx.x & 63;
    const int wv = threadIdx.x >> 6;      // wave owns output cols [wv*64, +64)
    const int l15 = lane & 15;
    const int kg = lane >> 4;             // k-group 0..3
    const int m0 = blockIdx.x * 32;
    const int pbase = wv * 64;
    const int pt0 = wv * 4;               // first B fragment-tile index
    const u16* Kr = Kcomb + (size_t)(blockIdx.x & 7) * 131072;  // XCD replica

    // ---- async stage x=[agg|h] rows -> swizzled LDS (1 row / issue) ----
    {
        int j0 = lane * 8;                       // dest u16 offset in row
#pragma unroll
        for (int i = 0; i < 8; ++i) {
            int m = i * 4 + wv;                  // 0..31
            int row = m0 + m;
            if (row >= N) row = N - 1;           // clamp; masked at store
            int ks = j0 ^ ((m & 7) << 3);        // pre-swizzled source k
            const u16* src = (j0 < 256)
                ? agg_bf + (size_t)row * 512 + ks
                : h_bf + (size_t)row * 256 + (ks - 256);
            gload_lds16(src, &xs[m * 512]);
        }
    }
    __syncthreads();   // drains global_load_lds; also fences in-place d_out use

    f32x4 acc[2][4];
#pragma unroll
    for (int f = 0; f < 2; ++f)
#pragma unroll
        for (int nf = 0; nf < 4; ++nf) acc[f][nf] = (f32x4)(0.f);

    const int swz = (l15 & 7) << 3;
#pragma unroll 4
    for (int k0 = 0; k0 < 512; k0 += 32) {
        int kk = k0 + kg * 8;
        int ksi = k0 >> 5;
        bf16x8 a[2], b[4];
#pragma unroll
        for (int f = 0; f < 2; ++f)
            a[f] = *(const bf16x8*)&xs[(f * 16 + l15) * 512 + (kk ^ swz)];
#pragma unroll
        for (int nf = 0; nf < 4; ++nf)
            b[nf] = *(const bf16x8*)(Kr + (size_t)((pt0 + nf) * 16 + ksi) * 512 + lane * 8);
#pragma unroll
        for (int f = 0; f < 2; ++f)
#pragma unroll
            for (int nf = 0; nf < 4; ++nf)
                acc[f][nf] = __builtin_amdgcn_mfma_f32_16x16x32_bf16(a[f], b[nf], acc[f][nf], 0, 0, 0);
    }

    // ---- epilogue: y = acc + c0[p] + c1[p]*wsum[row] ----
    float b0[4], b1[4];
#pragma unroll
    for (int nf = 0; nf < 4; ++nf) {
        int p = pbase + nf * 16 + l15;
        b0[nf] = c0[p];
        b1[nf] = c1[p];
    }
#pragma unroll
    for (int f = 0; f < 2; ++f) {
#pragma unroll
        for (int r = 0; r < 4; ++r) {
            int row = m0 + f * 16 + kg * 4 + r;
            if (row >= N) continue;
            float wsv = wsum_arr[row];
#pragma unroll
            for (int nf = 0; nf < 4; ++nf) {
                int p = pbase + nf * 16 + l15;
                dio[(size_t)row * 256 + p] = acc[f][nf][r] + b0[nf] + b1[nf] * wsv;
            }
        }
    }
}

// Fallback (no bf16 workspace): register GEMM, packed-B, barrier before epilogue.
__global__ __launch_bounds__(256, 4) void gemm_reg_kernel(
    float* __restrict__ dio, const u16* __restrict__ agg_bf,
    const u16* __restrict__ Kcomb,
    const float* __restrict__ h,
    const float* __restrict__ wsum_arr,
    const float* __restrict__ c0, const float* __restrict__ c1, int N) {
    const int lane = threadIdx.x & 63;
    const int wv = threadIdx.x >> 6;
    const int l15 = lane & 15;
    const int kg = lane >> 4;
    const int m0 = blockIdx.x * 32;
    const int pbase = wv * 64;
    const int pt0 = wv * 4;

    f32x4 acc[2][4];
#pragma unroll
    for (int f = 0; f < 2; ++f)
#pragma unroll
        for (int nf = 0; nf < 4; ++nf) acc[f][nf] = (f32x4)(0.f);

    int rowA[2];
#pragma unroll
    for (int f = 0; f < 2; ++f) {
        int r = m0 + f * 16 + l15;
        rowA[f] = (r < N) ? r : (N - 1);
    }
    const u16* Kr = Kcomb + (size_t)(blockIdx.x & 7) * 131072;

#pragma unroll 2
    for (int k0 = 0; k0 < 256; k0 += 32) {
        int kk = k0 + kg * 8;
        int ksi = k0 >> 5;
        bf16x8 a[2], b[4];
#pragma unroll
        for (int f = 0; f < 2; ++f)
            a[f] = *(const bf16x8*)(agg_bf + (size_t)rowA[f] * 512 + kk);
#pragma unroll
        for (int nf = 0; nf < 4; ++nf)
            b[nf] = *(const bf16x8*)(Kr + (size_t)((pt0 + nf) * 16 + ksi) * 512 + lane * 8);
#pragma unroll
        for (int f = 0; f < 2; ++f)
#pragma unroll
            for (int nf = 0; nf < 4; ++nf)
                acc[f][nf] = __builtin_amdgcn_mfma_f32_16x16x32_bf16(a[f], b[nf], acc[f][nf], 0, 0, 0);
    }
#pragma unroll 2
    for (int k0 = 256; k0 < 512; k0 += 32) {
        int kh = (k0 - 256) + kg * 8;
        int ksi = k0 >> 5;
        bf16x8 a[2], b[4];
#pragma unroll
        for (int f = 0; f < 2; ++f) {
            const float* hp = h + (size_t)rowA[f] * 256 + kh;
            float4 f0 = *(const float4*)hp, f1 = *(const float4*)(hp + 4);
            u16 tmp[8] = {f2bf(f0.x), f2bf(f0.y), f2bf(f0.z), f2bf(f0.w),
                          f2bf(f1.x), f2bf(f1.y), f2bf(f1.z), f2bf(f1.w)};
            a[f] = *(const bf16x8*)tmp;
        }
#pragma unroll
        for (int nf = 0; nf < 4; ++nf)
            b[nf] = *(const bf16x8*)(Kr + (size_t)((pt0 + nf) * 16 + ksi) * 512 + lane * 8);
#pragma unroll
        for (int f = 0; f < 2; ++f)
#pragma unroll
            for (int nf = 0; nf < 4; ++nf)
                acc[f][nf] = __builtin_amdgcn_mfma_f32_16x16x32_bf16(a[f], b[nf], acc[f][nf], 0, 0, 0);
    }

    __syncthreads();   // all waves done reading agg before in-place overwrite

    float b0[4], b1[4];
#pragma unroll
    for (int nf = 0; nf < 4; ++nf) {
        int p = pbase + nf * 16 + l15;
        b0[nf] = c0[p];
        b1[nf] = c1[p];
    }
#pragma unroll
    for (int f = 0; f < 2; ++f) {
#pragma unroll
        for (int r = 0; r < 4; ++r) {
            int row = m0 + f * 16 + kg * 4 + r;
            if (row >= N) continue;
            float wsv = wsum_arr[row];
#pragma unroll
            for (int nf = 0; nf < 4; ++nf) {
                int p = pbase + nf * 16 + l15;
                dio[(size_t)row * 256 + p] = acc[f][nf][r] + b0[nf] + b1[nf] * wsv;
            }
        }
    }
}

static inline size_t align4(size_t x) { return (x + 3) & ~(size_t)3; }

extern "C" void kernel_launch(void* const* d_in, const int* in_sizes, int n_in,
                              void* d_out, int out_size, void* d_ws, size_t ws_size,
                              hipStream_t stream) {
    const float* h       = (const float*)d_in[0];
    const int*   ei      = (const int*)d_in[1];   // (2,E) row-major
    const int*   et      = (const int*)d_in[2];
    const float* rel_emb = (const float*)d_in[3];
    const float* msg_w   = (const float*)d_in[4];
    const float* msg_b   = (const float*)d_in[5];
    const float* upd_w   = (const float*)d_in[6];
    const float* upd_b   = (const float*)d_in[7];
    const float* gate_w  = (const float*)d_in[8];
    const float* gate_b  = (const float*)d_in[9];

    const int N = in_sizes[0] / 256;
    const int E = in_sizes[2];
    const int R = in_sizes[3] / 256;

    // workspace layout (u32 units); total+deg_src+deg_dst contiguous for memset
    u32* ws = (u32*)d_ws;
    size_t o = 0;
    u32* total    = ws + o; o += 4;
    u32* deg_src  = ws + o; o += align4((size_t)N);
    u32* deg_dst  = ws + o; o += align4((size_t)N);
    u32* offs     = ws + o; o += align4((size_t)N);
    u32* cursor   = ws + o; o += align4((size_t)N);
    float* wsum   = (float*)(ws + o); o += align4((size_t)N);
    float* gate   = (float*)(ws + o); o += align4((size_t)R);
    uint2* edata  = (uint2*)(ws + o); o += (size_t)2 * E;
    float* Mf     = (float*)(ws + o); o += 65536;   // 256x256 fp32
    u16* Kcomb    = (u16*)(ws + o); o += 524288;    // 8 x 256KB fragment-packed
    float* c0     = (float*)(ws + o); o += 256;
    float* c1     = (float*)(ws + o); o += 256;
    size_t need_base = o;
    u16* h_bf     = (u16*)(ws + o); o += (size_t)N * 128;
    u16* rel_bf   = (u16*)(ws + o); o += (size_t)R * 128;
    size_t need_bf = o;

    if (ws_size < need_base * 4) return;  // insufficient scratch -> fail loudly
    const bool use_bf = (ws_size >= need_bf * 4);

    float* out = (float*)d_out;
    u16* agg_bf = (u16*)d_out;   // bf16 rows at u16 stride 512 (half of each slot)

    // zero total + degree counters (contiguous)
    hipMemsetAsync(total, 0, (4 + 2 * align4((size_t)N)) * 4, stream);

    build_m_kernel<<<256, 256, 0, stream>>>(msg_w, Mf);
    build_comb_kernel<<<256, 256, 0, stream>>>(upd_w, upd_b, msg_b, Mf, Kcomb, c0, c1);
    gate_kernel<<<(R + 3) / 4, 256, 0, stream>>>(rel_emb, gate_w, gate_b, gate, R);
    degree_kernel<<<(E + 255) / 256, 256, 0, stream>>>(ei, E, deg_src, deg_dst);
    alloc_kernel<<<(N + 255) / 256, 256, 0, stream>>>(deg_dst, offs, cursor, total, N);
    if (use_bf) {
        tobf_kernel<<<1024, 256, 0, stream>>>(h, h_bf, N * 32);       // N*256/8
        tobf_kernel<<<64, 256, 0, stream>>>(rel_emb, rel_bf, R * 32); // R*256/8
    }
    fill_kernel<<<(E + 255) / 256, 256, 0, stream>>>(ei, et, deg_src, deg_dst, gate,
                                                     cursor, edata, E);
    if (use_bf) {
        agg_kernel<1><<<(N + 3) / 4, 256, 0, stream>>>(h, h_bf, rel_emb, rel_bf, offs,
                                                       deg_dst, edata, agg_bf, wsum, N);
        gemm_lds_kernel<<<(N + 31) / 32, 256, 0, stream>>>(out, agg_bf, Kcomb, h_bf,
                                                           wsum, c0, c1, N);
    } else {
        agg_kernel<0><<<(N + 3) / 4, 256, 0, stream>>>(h, h_bf, rel_emb, rel_bf, offs,
                                                       deg_dst, edata, agg_bf, wsum, N);
        gemm_reg_kernel<<<(N + 31) / 32, 256, 0, stream>>>(out, agg_bf, Kcomb, h,
                                                           wsum, c0, c1, N);
    }
}

// Round 11
// 254.782 us; speedup vs baseline: 1.4027x; 1.0141x over previous
//
#include <hip/hip_runtime.h>
#include <math.h>

typedef unsigned int u32;
typedef unsigned short u16;
typedef __attribute__((ext_vector_type(8))) short bf16x8;   // 8 bf16 in 4 VGPRs
typedef __attribute__((ext_vector_type(4))) float f32x4;

#define GLOBAL_AS __attribute__((address_space(1)))
#define LDS_AS __attribute__((address_space(3)))

__device__ __forceinline__ void gload_lds16(const void* g, void* s) {
    __builtin_amdgcn_global_load_lds((const GLOBAL_AS void*)g, (LDS_AS void*)s, 16, 0, 0);
}

__device__ inline u16 f2bf(float x) {  // round-to-nearest-even
    union { float f; u32 u; } v; v.f = x;
    u32 r = v.u + 0x7FFFu + ((v.u >> 16) & 1u);
    return (u16)(r >> 16);
}
__device__ inline float bf_lo(u32 u) { return __uint_as_float(u << 16); }
__device__ inline float bf_hi(u32 u) { return __uint_as_float(u & 0xffff0000u); }

// ---------------------------------------------------------------------------
// Clifford GNN message passing, fully linearized:
//   agg[n] = sum_e w_e*(h[src] .* r[rel]),  w_e = gate(rel)*norm(e)
//   out    = (Ku.Km).agg + Ku.h + ws*(Ku.msg_b) + upd_b
// agg: 2 nodes/wave (32 lanes x 16B each), predicated x4-unrolled edge loop
//      (clamped duplicate gathers instead of serial tail). NOTE: every lane
//      accumulates the FULL per-node wsum already -- lane 0 writes it
//      directly, NO cross-lane reduction (round-10 bug: reduced 32 copies
//      -> 32x wsum -> absmax 6.3).
// GEMM: K=512 on x=[agg|h]; Kcomb fragment-packed (1KB coalesced B loads),
//      replicated 8x (per-XCD L2); A staged via async global_load_lds into
//      swizzled 32KB LDS; 4 blocks/CU.
// ---------------------------------------------------------------------------

// Mf[k*256+i] = M[k][i] fp32 (message Clifford matrix, row k = output idx)
__global__ void build_m_kernel(const float* __restrict__ msg_w, float* __restrict__ Mf) {
    const int   s_tab[16] = {0,1,2,3, 1,0,3,2, 2,3,0,1, 3,2,1,0};
    const float g_tab[16] = {1.f,1.f,1.f,-1.f, 1.f,1.f,-1.f,1.f,
                             1.f,1.f,1.f,-1.f, 1.f,1.f,1.f,1.f};
    int idx = blockIdx.x * 256 + threadIdx.x;   // idx = k*256 + i
    int k = idx >> 8, i = idx & 255;
    int ob = k >> 6, oc = k & 63, ib = i >> 6, ic = i & 63;
    int t = ob * 4 + ib;
    Mf[idx] = g_tab[t] * msg_w[s_tab[t] * 4096 + oc * 64 + ic];
}

// Block p builds output-permuted row p of Kcomb in FRAGMENT-PACKED layout,
// 8 replicas, + c0[p], c1[p].   j = (p&3)*64 + (p>>2)
// Row p, col k (k<256: (U.M)[j][k]; k>=256: U[j][k-256]).
// Fragment address (u16): frag_id = (p>>4)*16 + (k>>5); lane = ((k>>3)&3)*16 + (p&15);
//   addr = frag_id*512 + lane*8 + (k&7)
__global__ __launch_bounds__(256) void build_comb_kernel(
    const float* __restrict__ upd_w, const float* __restrict__ upd_b,
    const float* __restrict__ msg_b, const float* __restrict__ Mf,
    u16* __restrict__ Kcomb, float* __restrict__ c0, float* __restrict__ c1) {
    const int   s_tab[16] = {0,1,2,3, 1,0,3,2, 2,3,0,1, 3,2,1,0};
    const float g_tab[16] = {1.f,1.f,1.f,-1.f, 1.f,1.f,-1.f,1.f,
                             1.f,1.f,1.f,-1.f, 1.f,1.f,1.f,1.f};
    __shared__ float U_s[256];
    __shared__ float wred[4];
    int p = blockIdx.x;
    int j = (p & 3) * 64 + (p >> 2);
    int tid = threadIdx.x;                 // tid = k in 0..255
    {
        int ob = j >> 6, oc = j & 63, ib = tid >> 6, ic = tid & 63;
        int t = ob * 4 + ib;
        U_s[tid] = g_tab[t] * upd_w[s_tab[t] * 4096 + oc * 64 + ic];
    }
    __syncthreads();
    float acc = 0.f;
#pragma unroll 8
    for (int k = 0; k < 256; ++k) acc += U_s[k] * Mf[k * 256 + tid];
    u16 vA = f2bf(acc);          // element (p, k=tid)
    u16 vU = f2bf(U_s[tid]);     // element (p, k=tid+256)
    int pt = p >> 4, l15 = p & 15;
    int kgA = (tid >> 3) & 3, elA = tid & 7;
    size_t addrA = (size_t)(pt * 16 + (tid >> 5)) * 512 + (kgA * 16 + l15) * 8 + elA;
    int ku = tid + 256;
    size_t addrU = (size_t)(pt * 16 + (ku >> 5)) * 512 + (kgA * 16 + l15) * 8 + elA;
#pragma unroll
    for (int r = 0; r < 8; ++r) {        // 8 replicas (one per XCD's L2)
        Kcomb[(size_t)r * 131072 + addrA] = vA;
        Kcomb[(size_t)r * 131072 + addrU] = vU;
    }
    float part = U_s[tid] * msg_b[tid];
    int lane = tid & 63, wv = tid >> 6;
#pragma unroll
    for (int d = 32; d > 0; d >>= 1) part += __shfl_down(part, d);
    if (lane == 0) wred[wv] = part;
    __syncthreads();
    if (tid == 0) { c1[p] = wred[0] + wred[1] + wred[2] + wred[3]; c0[p] = upd_b[j]; }
}

// gate[r] = sigmoid( sum_j rel_emb[r, j] * gate_w[(j&63)*4 + (j>>6)] + gate_b )
__global__ void gate_kernel(const float* __restrict__ rel_emb,
                            const float* __restrict__ gate_w,
                            const float* __restrict__ gate_b,
                            float* __restrict__ gate, int R) {
    int wv = threadIdx.x >> 6, lane = threadIdx.x & 63;
    int r = blockIdx.x * 4 + wv;
    if (r >= R) return;
    float4 rv = *(const float4*)(rel_emb + (size_t)r * 256 + lane * 4);
    float s = 0.f;
    float rvv[4] = {rv.x, rv.y, rv.z, rv.w};
#pragma unroll
    for (int c = 0; c < 4; ++c) {
        int j = lane * 4 + c;
        s += rvv[c] * gate_w[(j & 63) * 4 + (j >> 6)];
    }
#pragma unroll
    for (int d = 32; d > 0; d >>= 1) s += __shfl_down(s, d);
    if (lane == 0) gate[r] = 1.0f / (1.0f + expf(-(s + gate_b[0])));
}

__global__ void degree_kernel(const int* __restrict__ ei, int E,
                              u32* __restrict__ deg_src, u32* __restrict__ deg_dst) {
    int e = blockIdx.x * 256 + threadIdx.x;
    if (e >= E) return;
    atomicAdd(&deg_src[ei[e]], 1u);
    atomicAdd(&deg_dst[ei[E + e]], 1u);
}

// Parallel bucket allocator (order irrelevant, only disjointness matters).
__global__ void alloc_kernel(const u32* __restrict__ deg, u32* __restrict__ offs,
                             u32* __restrict__ cursor, u32* __restrict__ total, int N) {
    __shared__ u32 wt[4];
    __shared__ u32 bbase;
    int tid = threadIdx.x, lane = tid & 63, wv = tid >> 6;
    int i = blockIdx.x * 256 + tid;
    u32 d = (i < N) ? deg[i] : 0u;
    u32 sc = d;
#pragma unroll
    for (int s = 1; s < 64; s <<= 1) { u32 o = __shfl_up(sc, s); if (lane >= s) sc += o; }
    if (lane == 63) wt[wv] = sc;
    __syncthreads();
    if (tid == 0) bbase = atomicAdd(total, wt[0] + wt[1] + wt[2] + wt[3]);
    __syncthreads();
    u32 wpre = 0;
    for (int w = 0; w < wv; ++w) wpre += wt[w];
    u32 off = bbase + wpre + sc - d;
    if (i < N) { offs[i] = off; cursor[i] = off; }
}

// Bucket-fill, packed metadata: edata[pos] = {src | rel<<18, w_bits}  (8B/edge).
__global__ void fill_kernel(const int* __restrict__ ei, const int* __restrict__ et,
                            const u32* __restrict__ deg_src,
                            const u32* __restrict__ deg_dst,
                            const float* __restrict__ gate,
                            u32* __restrict__ cursor, uint2* __restrict__ edata, int E) {
    int e = blockIdx.x * 256 + threadIdx.x;
    if (e >= E) return;
    int src = ei[e];
    int dst = ei[E + e];
    int rel = et[e];
    float w = gate[rel] * rsqrtf(fmaxf((float)deg_src[src] * (float)deg_dst[dst], 1.0f));
    u32 pos = atomicAdd(&cursor[dst], 1u);
    edata[pos] = make_uint2((u32)src | ((u32)rel << 18), __float_as_uint(w));
}

// fp32 -> bf16 bulk convert (8 elems/thread, grid-stride).
__global__ void tobf_kernel(const float* __restrict__ src, u16* __restrict__ dst, int n8) {
    for (int i = blockIdx.x * 256 + threadIdx.x; i < n8; i += gridDim.x * 256) {
        const float* p = src + (size_t)i * 8;
        float4 a = *(const float4*)(p);
        float4 b = *(const float4*)(p + 4);
        u16 tmp[8] = {f2bf(a.x), f2bf(a.y), f2bf(a.z), f2bf(a.w),
                      f2bf(b.x), f2bf(b.y), f2bf(b.z), f2bf(b.w)};
        *(uint4*)(dst + (size_t)i * 8) = *(const uint4*)tmp;
    }
}

// 2 nodes per wave (lanes 0-31 = node A, 32-63 = node B; 16B/lane).
// Predicated x4-unrolled edge loop: always 4 gather-pairs in flight,
// tail edges use clamped index (cache-hit duplicate) with zero weight.
// Every lane accumulates the full per-node wsum; lane l32==0 writes it
// directly (no reduction!).
template <int BF>
__global__ __launch_bounds__(256) void agg_kernel(
    const float* __restrict__ h, const u16* __restrict__ h_bf,
    const float* __restrict__ rel_emb, const u16* __restrict__ rel_bf,
    const u32* __restrict__ offs, const u32* __restrict__ deg_dst,
    const uint2* __restrict__ edata,
    u16* __restrict__ agg_bf, float* __restrict__ wsum_arr, int N) {
    int wv = threadIdx.x >> 6, lane = threadIdx.x & 63;
    int half = lane >> 5, l32 = lane & 31;
    int n = (blockIdx.x * 4 + wv) * 2 + half;
    bool valid = n < N;
    u32 off = valid ? offs[n] : 0u;
    u32 dd  = valid ? deg_dst[n] : 0u;
    float acc[8];
#pragma unroll
    for (int j = 0; j < 8; ++j) acc[j] = 0.f;
    float wsum = 0.f;

    for (u32 e = 0; e < dd; e += 4) {
        uint2 d[4];
        uint4 hv[4], rv[4];
        float wq[4];
#pragma unroll
        for (int q = 0; q < 4; ++q) {
            u32 idx = e + q;
            u32 cl = (idx < dd) ? idx : (dd - 1);   // clamp -> dup line, cache hit
            d[q] = edata[off + cl];
            wq[q] = (idx < dd) ? __uint_as_float(d[q].y) : 0.f;
        }
#pragma unroll
        for (int q = 0; q < 4; ++q) {
            u32 src = d[q].x & 0x3FFFFu, rel = d[q].x >> 18;
            if (BF) {
                hv[q] = *(const uint4*)(h_bf + (size_t)src * 256 + l32 * 8);
                rv[q] = *(const uint4*)(rel_bf + (size_t)rel * 256 + l32 * 8);
            } else {
                const float* hp = h + (size_t)src * 256 + l32 * 8;
                const float* rp = rel_emb + (size_t)rel * 256 + l32 * 8;
                float4 hf0 = *(const float4*)hp, hf1 = *(const float4*)(hp + 4);
                float4 rf0 = *(const float4*)rp, rf1 = *(const float4*)(rp + 4);
                u16 th[8] = {f2bf(hf0.x), f2bf(hf0.y), f2bf(hf0.z), f2bf(hf0.w),
                             f2bf(hf1.x), f2bf(hf1.y), f2bf(hf1.z), f2bf(hf1.w)};
                u16 tr[8] = {f2bf(rf0.x), f2bf(rf0.y), f2bf(rf0.z), f2bf(rf0.w),
                             f2bf(rf1.x), f2bf(rf1.y), f2bf(rf1.z), f2bf(rf1.w)};
                hv[q] = *(const uint4*)th;
                rv[q] = *(const uint4*)tr;
            }
        }
#pragma unroll
        for (int q = 0; q < 4; ++q) {
            float w = wq[q];
            u32 hu[4] = {hv[q].x, hv[q].y, hv[q].z, hv[q].w};
            u32 ru[4] = {rv[q].x, rv[q].y, rv[q].z, rv[q].w};
#pragma unroll
            for (int c = 0; c < 4; ++c) {
                acc[c * 2 + 0] += w * bf_lo(hu[c]) * bf_lo(ru[c]);
                acc[c * 2 + 1] += w * bf_hi(hu[c]) * bf_hi(ru[c]);
            }
            wsum += w;
        }
    }

    if (valid) {
        u32 outw[4];
#pragma unroll
        for (int c = 0; c < 4; ++c)
            outw[c] = (u32)f2bf(acc[c * 2]) | ((u32)f2bf(acc[c * 2 + 1]) << 16);
        *(uint4*)(agg_bf + (size_t)n * 512 + l32 * 8) = *(const uint4*)outw;
        if (l32 == 0) wsum_arr[n] = wsum;   // already the full sum per lane
    }
}

// LDS-staged K=512 GEMM. Block = 32 rows x 256 cols; 4 waves, each 32x64
// (acc 2x4 frags, ~90 regs -> 4 waves/SIMD; 32KB LDS -> 4 blocks/CU).
// x=[agg|h] staged async into swizzled LDS via global_load_lds (dest linear,
// per-lane SOURCE pre-swizzled). B = fragment-packed Kcomb: each load is
// 64 lanes x 16B contiguous (1KB coalesced burst) from the XCD-local replica.
// out[row][p] = acc + c0[p] + c1[p]*wsum[row].
__global__ __launch_bounds__(256, 4) void gemm_lds_kernel(
    float* __restrict__ dio, const u16* __restrict__ agg_bf,
    const u16* __restrict__ Kcomb, const u16* __restrict__ h_bf,
    const float* __restrict__ wsum_arr,
    const float* __restrict__ c0, const float* __restrict__ c1, int N) {
    __shared__ __align__(16) u16 xs[32 * 512];   // 32 KiB
    const int lane = threadIdx.x & 63;
    const int wv = threadIdx.x >> 6;      // wave owns output cols [wv*64, +64)
    const int l15 = lane & 15;
    const int kg = lane >> 4;             // k-group 0..3
    const int m0 = blockIdx.x * 32;
    const int pbase = wv * 64;
    const int pt0 = wv * 4;               // first B fragment-tile index
    const u16* Kr = Kcomb + (size_t)(blockIdx.x & 7) * 131072;  // XCD replica

    // ---- async stage x=[agg|h] rows -> swizzled LDS (1 row / issue) ----
    {
        int j0 = lane * 8;                       // dest u16 offset in row
#pragma unroll
        for (int i = 0; i < 8; ++i) {
            int m = i * 4 + wv;                  // 0..31
            int row = m0 + m;
            if (row >= N) row = N - 1;           // clamp; masked at store
            int ks = j0 ^ ((m & 7) << 3);        // pre-swizzled source k
            const u16* src = (j0 < 256)
                ? agg_bf + (size_t)row * 512 + ks
                : h_bf + (size_t)row * 256 + (ks - 256);
            gload_lds16(src, &xs[m * 512]);
        }
    }
    __syncthreads();   // drains global_load_lds; also fences in-place d_out use

    f32x4 acc[2][4];
#pragma unroll
    for (int f = 0; f < 2; ++f)
#pragma unroll
        for (int nf = 0; nf < 4; ++nf) acc[f][nf] = (f32x4)(0.f);

    const int swz = (l15 & 7) << 3;
#pragma unroll 4
    for (int k0 = 0; k0 < 512; k0 += 32) {
        int kk = k0 + kg * 8;
        int ksi = k0 >> 5;
        bf16x8 a[2], b[4];
#pragma unroll
        for (int f = 0; f < 2; ++f)
            a[f] = *(const bf16x8*)&xs[(f * 16 + l15) * 512 + (kk ^ swz)];
#pragma unroll
        for (int nf = 0; nf < 4; ++nf)
            b[nf] = *(const bf16x8*)(Kr + (size_t)((pt0 + nf) * 16 + ksi) * 512 + lane * 8);
#pragma unroll
        for (int f = 0; f < 2; ++f)
#pragma unroll
            for (int nf = 0; nf < 4; ++nf)
                acc[f][nf] = __builtin_amdgcn_mfma_f32_16x16x32_bf16(a[f], b[nf], acc[f][nf], 0, 0, 0);
    }

    // ---- epilogue: y = acc + c0[p] + c1[p]*wsum[row] ----
    float b0[4], b1[4];
#pragma unroll
    for (int nf = 0; nf < 4; ++nf) {
        int p = pbase + nf * 16 + l15;
        b0[nf] = c0[p];
        b1[nf] = c1[p];
    }
#pragma unroll
    for (int f = 0; f < 2; ++f) {
#pragma unroll
        for (int r = 0; r < 4; ++r) {
            int row = m0 + f * 16 + kg * 4 + r;
            if (row >= N) continue;
            float wsv = wsum_arr[row];
#pragma unroll
            for (int nf = 0; nf < 4; ++nf) {
                int p = pbase + nf * 16 + l15;
                dio[(size_t)row * 256 + p] = acc[f][nf][r] + b0[nf] + b1[nf] * wsv;
            }
        }
    }
}

// Fallback (no bf16 workspace): register GEMM, packed-B, barrier before epilogue.
__global__ __launch_bounds__(256, 4) void gemm_reg_kernel(
    float* __restrict__ dio, const u16* __restrict__ agg_bf,
    const u16* __restrict__ Kcomb,
    const float* __restrict__ h,
    const float* __restrict__ wsum_arr,
    const float* __restrict__ c0, const float* __restrict__ c1, int N) {
    const int lane = threadIdx.x & 63;
    const int wv = threadIdx.x >> 6;
    const int l15 = lane & 15;
    const int kg = lane >> 4;
    const int m0 = blockIdx.x * 32;
    const int pbase = wv * 64;
    const int pt0 = wv * 4;

    f32x4 acc[2][4];
#pragma unroll
    for (int f = 0; f < 2; ++f)
#pragma unroll
        for (int nf = 0; nf < 4; ++nf) acc[f][nf] = (f32x4)(0.f);

    int rowA[2];
#pragma unroll
    for (int f = 0; f < 2; ++f) {
        int r = m0 + f * 16 + l15;
        rowA[f] = (r < N) ? r : (N - 1);
    }
    const u16* Kr = Kcomb + (size_t)(blockIdx.x & 7) * 131072;

#pragma unroll 2
    for (int k0 = 0; k0 < 256; k0 += 32) {
        int kk = k0 + kg * 8;
        int ksi = k0 >> 5;
        bf16x8 a[2], b[4];
#pragma unroll
        for (int f = 0; f < 2; ++f)
            a[f] = *(const bf16x8*)(agg_bf + (size_t)rowA[f] * 512 + kk);
#pragma unroll
        for (int nf = 0; nf < 4; ++nf)
            b[nf] = *(const bf16x8*)(Kr + (size_t)((pt0 + nf) * 16 + ksi) * 512 + lane * 8);
#pragma unroll
        for (int f = 0; f < 2; ++f)
#pragma unroll
            for (int nf = 0; nf < 4; ++nf)
                acc[f][nf] = __builtin_amdgcn_mfma_f32_16x16x32_bf16(a[f], b[nf], acc[f][nf], 0, 0, 0);
    }
#pragma unroll 2
    for (int k0 = 256; k0 < 512; k0 += 32) {
        int kh = (k0 - 256) + kg * 8;
        int ksi = k0 >> 5;
        bf16x8 a[2], b[4];
#pragma unroll
        for (int f = 0; f < 2; ++f) {
            const float* hp = h + (size_t)rowA[f] * 256 + kh;
            float4 f0 = *(const float4*)hp, f1 = *(const float4*)(hp + 4);
            u16 tmp[8] = {f2bf(f0.x), f2bf(f0.y), f2bf(f0.z), f2bf(f0.w),
                          f2bf(f1.x), f2bf(f1.y), f2bf(f1.z), f2bf(f1.w)};
            a[f] = *(const bf16x8*)tmp;
        }
#pragma unroll
        for (int nf = 0; nf < 4; ++nf)
            b[nf] = *(const bf16x8*)(Kr + (size_t)((pt0 + nf) * 16 + ksi) * 512 + lane * 8);
#pragma unroll
        for (int f = 0; f < 2; ++f)
#pragma unroll
            for (int nf = 0; nf < 4; ++nf)
                acc[f][nf] = __builtin_amdgcn_mfma_f32_16x16x32_bf16(a[f], b[nf], acc[f][nf], 0, 0, 0);
    }

    __syncthreads();   // all waves done reading agg before in-place overwrite

    float b0[4], b1[4];
#pragma unroll
    for (int nf = 0; nf < 4; ++nf) {
        int p = pbase + nf * 16 + l15;
        b0[nf] = c0[p];
        b1[nf] = c1[p];
    }
#pragma unroll
    for (int f = 0; f < 2; ++f) {
#pragma unroll
        for (int r = 0; r < 4; ++r) {
            int row = m0 + f * 16 + kg * 4 + r;
            if (row >= N) continue;
            float wsv = wsum_arr[row];
#pragma unroll
            for (int nf = 0; nf < 4; ++nf) {
                int p = pbase + nf * 16 + l15;
                dio[(size_t)row * 256 + p] = acc[f][nf][r] + b0[nf] + b1[nf] * wsv;
            }
        }
    }
}

static inline size_t align4(size_t x) { return (x + 3) & ~(size_t)3; }

extern "C" void kernel_launch(void* const* d_in, const int* in_sizes, int n_in,
                              void* d_out, int out_size, void* d_ws, size_t ws_size,
                              hipStream_t stream) {
    const float* h       = (const float*)d_in[0];
    const int*   ei      = (const int*)d_in[1];   // (2,E) row-major
    const int*   et      = (const int*)d_in[2];
    const float* rel_emb = (const float*)d_in[3];
    const float* msg_w   = (const float*)d_in[4];
    const float* msg_b   = (const float*)d_in[5];
    const float* upd_w   = (const float*)d_in[6];
    const float* upd_b   = (const float*)d_in[7];
    const float* gate_w  = (const float*)d_in[8];
    const float* gate_b  = (const float*)d_in[9];

    const int N = in_sizes[0] / 256;
    const int E = in_sizes[2];
    const int R = in_sizes[3] / 256;

    // workspace layout (u32 units); total+deg_src+deg_dst contiguous for memset
    u32* ws = (u32*)d_ws;
    size_t o = 0;
    u32* total    = ws + o; o += 4;
    u32* deg_src  = ws + o; o += align4((size_t)N);
    u32* deg_dst  = ws + o; o += align4((size_t)N);
    u32* offs     = ws + o; o += align4((size_t)N);
    u32* cursor   = ws + o; o += align4((size_t)N);
    float* wsum   = (float*)(ws + o); o += align4((size_t)N);
    float* gate   = (float*)(ws + o); o += align4((size_t)R);
    uint2* edata  = (uint2*)(ws + o); o += (size_t)2 * E;
    float* Mf     = (float*)(ws + o); o += 65536;   // 256x256 fp32
    u16* Kcomb    = (u16*)(ws + o); o += 524288;    // 8 x 256KB fragment-packed
    float* c0     = (float*)(ws + o); o += 256;
    float* c1     = (float*)(ws + o); o += 256;
    size_t need_base = o;
    u16* h_bf     = (u16*)(ws + o); o += (size_t)N * 128;
    u16* rel_bf   = (u16*)(ws + o); o += (size_t)R * 128;
    size_t need_bf = o;

    if (ws_size < need_base * 4) return;  // insufficient scratch -> fail loudly
    const bool use_bf = (ws_size >= need_bf * 4);

    float* out = (float*)d_out;
    u16* agg_bf = (u16*)d_out;   // bf16 rows at u16 stride 512 (half of each slot)

    // zero total + degree counters (contiguous)
    hipMemsetAsync(total, 0, (4 + 2 * align4((size_t)N)) * 4, stream);

    build_m_kernel<<<256, 256, 0, stream>>>(msg_w, Mf);
    build_comb_kernel<<<256, 256, 0, stream>>>(upd_w, upd_b, msg_b, Mf, Kcomb, c0, c1);
    gate_kernel<<<(R + 3) / 4, 256, 0, stream>>>(rel_emb, gate_w, gate_b, gate, R);
    degree_kernel<<<(E + 255) / 256, 256, 0, stream>>>(ei, E, deg_src, deg_dst);
    alloc_kernel<<<(N + 255) / 256, 256, 0, stream>>>(deg_dst, offs, cursor, total, N);
    if (use_bf) {
        tobf_kernel<<<1024, 256, 0, stream>>>(h, h_bf, N * 32);       // N*256/8
        tobf_kernel<<<64, 256, 0, stream>>>(rel_emb, rel_bf, R * 32); // R*256/8
    }
    fill_kernel<<<(E + 255) / 256, 256, 0, stream>>>(ei, et, deg_src, deg_dst, gate,
                                                     cursor, edata, E);
    if (use_bf) {
        agg_kernel<1><<<(N + 7) / 8, 256, 0, stream>>>(h, h_bf, rel_emb, rel_bf, offs,
                                                       deg_dst, edata, agg_bf, wsum, N);
        gemm_lds_kernel<<<(N + 31) / 32, 256, 0, stream>>>(out, agg_bf, Kcomb, h_bf,
                                                           wsum, c0, c1, N);
    } else {
        agg_kernel<0><<<(N + 7) / 8, 256, 0, stream>>>(h, h_bf, rel_emb, rel_bf, offs,
                                                       deg_dst, edata, agg_bf, wsum, N);
        gemm_reg_kernel<<<(N + 31) / 32, 256, 0, stream>>>(out, agg_bf, Kcomb, h,
                                                           wsum, c0, c1, N);
    }
}

// Round 12
// 238.165 us; speedup vs baseline: 1.5006x; 1.0698x over previous
//
#include <hip/hip_runtime.h>
#include <math.h>

typedef unsigned int u32;
typedef unsigned short u16;
typedef __attribute__((ext_vector_type(8))) short bf16x8;   // 8 bf16 in 4 VGPRs
typedef __attribute__((ext_vector_type(4))) float f32x4;

#define GLOBAL_AS __attribute__((address_space(1)))
#define LDS_AS __attribute__((address_space(3)))

__device__ __forceinline__ void gload_lds16(const void* g, void* s) {
    __builtin_amdgcn_global_load_lds((const GLOBAL_AS void*)g, (LDS_AS void*)s, 16, 0, 0);
}

__device__ inline u16 f2bf(float x) {  // round-to-nearest-even
    union { float f; u32 u; } v; v.f = x;
    u32 r = v.u + 0x7FFFu + ((v.u >> 16) & 1u);
    return (u16)(r >> 16);
}
__device__ inline float bf_lo(u32 u) { return __uint_as_float(u << 16); }
__device__ inline float bf_hi(u32 u) { return __uint_as_float(u & 0xffff0000u); }

// ---------------------------------------------------------------------------
// Clifford GNN message passing, fully linearized:
//   agg[n] = sum_e w_e*(h[src] .* r[rel]),  w_e = gate(rel)*norm(e)
//   out    = (Ku.Km).agg + Ku.h + ws*(Ku.msg_b) + upd_b
// Pipeline (6 dispatches): memset -> prep (fused: Kcomb-builder + degree +
// gate + tobf(rel) + tobf(h), concurrent by block-range) -> alloc -> fill ->
// agg -> gemm.  Round-12 change: the ~9 small serial preprocessing dispatches
// (~135us incl. gaps) are fused so they overlap under tobf(h)'s HBM stream.
// ---------------------------------------------------------------------------

// Fused preprocessing. Block ranges:
//  [0,256)               : build row p of Kcomb (fragment-packed, 8 replicas)
//                          with M computed on-the-fly from msg_w; c0,c1.
//  [256, +nbDeg)         : degree atomics.
//  [.., +nbGate)         : gate[r] (4 rel/block).
//  [.., +nbRel)          : rel_emb -> rel_bf.
//  [.., +nbH)            : h -> h_bf (grid-stride over this sub-range).
template <int BF>
__global__ __launch_bounds__(256) void prep_kernel(
    const float* __restrict__ msg_w, const float* __restrict__ upd_w,
    const float* __restrict__ upd_b, const float* __restrict__ msg_b,
    const float* __restrict__ rel_emb, const float* __restrict__ gate_w,
    const float* __restrict__ gate_b, const float* __restrict__ h,
    const int* __restrict__ ei, int E,
    u32* __restrict__ deg_src, u32* __restrict__ deg_dst,
    float* __restrict__ gate, u16* __restrict__ Kcomb,
    float* __restrict__ c0, float* __restrict__ c1,
    u16* __restrict__ h_bf, u16* __restrict__ rel_bf,
    int N, int R, int nbDeg, int nbGate, int nbRel, int nbH) {
    const int s_tab[16] = {0,1,2,3, 1,0,3,2, 2,3,0,1, 3,2,1,0};
    const float g_tab[16] = {1.f,1.f,1.f,-1.f, 1.f,1.f,-1.f,1.f,
                             1.f,1.f,1.f,-1.f, 1.f,1.f,1.f,1.f};
    __shared__ float U_s[256];
    __shared__ float wred[4];
    int b = blockIdx.x;
    int tid = threadIdx.x;

    if (b < 256) {
        // ---- Kcomb row p = b: (U.M)[j][:] | U[j][:], fragment-packed ----
        int p = b;
        int j = (p & 3) * 64 + (p >> 2);
        int ib = tid >> 6, ic = tid & 63;
        {
            int t = (j >> 6) * 4 + ib;
            U_s[tid] = g_tab[t] * upd_w[s_tab[t] * 4096 + (j & 63) * 64 + ic];
        }
        __syncthreads();
        float acc = 0.f;
#pragma unroll
        for (int ob = 0; ob < 4; ++ob) {        // M on the fly (no Mf buffer)
            int t = ob * 4 + ib;
            int s = s_tab[t];
            float g = g_tab[t];
            const float* wp = msg_w + s * 4096 + ic;
            const float* us = U_s + ob * 64;
#pragma unroll 8
            for (int oc = 0; oc < 64; ++oc) acc += us[oc] * g * wp[oc * 64];
        }
        u16 vA = f2bf(acc);          // element (p, k=tid)
        u16 vU = f2bf(U_s[tid]);     // element (p, k=tid+256)
        int pt = p >> 4, pl = p & 15;
        int kgA = (tid >> 3) & 3, elA = tid & 7;
        size_t addrA = (size_t)(pt * 16 + (tid >> 5)) * 512 + (kgA * 16 + pl) * 8 + elA;
        int ku = tid + 256;
        size_t addrU = (size_t)(pt * 16 + (ku >> 5)) * 512 + (kgA * 16 + pl) * 8 + elA;
#pragma unroll
        for (int r = 0; r < 8; ++r) {        // 8 replicas (one per XCD's L2)
            Kcomb[(size_t)r * 131072 + addrA] = vA;
            Kcomb[(size_t)r * 131072 + addrU] = vU;
        }
        float part = U_s[tid] * msg_b[tid];
        int lane = tid & 63, wv = tid >> 6;
#pragma unroll
        for (int d = 32; d > 0; d >>= 1) part += __shfl_down(part, d);
        if (lane == 0) wred[wv] = part;
        __syncthreads();
        if (tid == 0) { c1[p] = wred[0] + wred[1] + wred[2] + wred[3]; c0[p] = upd_b[j]; }
        return;
    }
    b -= 256;
    if (b < nbDeg) {
        int e = b * 256 + tid;
        if (e < E) {
            atomicAdd(&deg_src[ei[e]], 1u);
            atomicAdd(&deg_dst[ei[E + e]], 1u);
        }
        return;
    }
    b -= nbDeg;
    if (b < nbGate) {
        int wv = tid >> 6, lane = tid & 63;
        int r = b * 4 + wv;
        if (r >= R) return;
        float4 rv = *(const float4*)(rel_emb + (size_t)r * 256 + lane * 4);
        float s = 0.f;
        float rvv[4] = {rv.x, rv.y, rv.z, rv.w};
#pragma unroll
        for (int c = 0; c < 4; ++c) {
            int jj = lane * 4 + c;
            s += rvv[c] * gate_w[(jj & 63) * 4 + (jj >> 6)];
        }
#pragma unroll
        for (int d = 32; d > 0; d >>= 1) s += __shfl_down(s, d);
        if (lane == 0) gate[r] = 1.0f / (1.0f + expf(-(s + gate_b[0])));
        return;
    }
    b -= nbGate;
    if (BF && b < nbRel) {
        int i = b * 256 + tid;
        if (i < R * 32) {
            const float* p8 = rel_emb + (size_t)i * 8;
            float4 a = *(const float4*)(p8);
            float4 bb = *(const float4*)(p8 + 4);
            u16 tmp[8] = {f2bf(a.x), f2bf(a.y), f2bf(a.z), f2bf(a.w),
                          f2bf(bb.x), f2bf(bb.y), f2bf(bb.z), f2bf(bb.w)};
            *(uint4*)(rel_bf + (size_t)i * 8) = *(const uint4*)tmp;
        }
        return;
    }
    b -= nbRel;
    if (BF) {
        int n8 = N * 32;
        for (int i = b * 256 + tid; i < n8; i += nbH * 256) {
            const float* p8 = h + (size_t)i * 8;
            float4 a = *(const float4*)(p8);
            float4 bb = *(const float4*)(p8 + 4);
            u16 tmp[8] = {f2bf(a.x), f2bf(a.y), f2bf(a.z), f2bf(a.w),
                          f2bf(bb.x), f2bf(bb.y), f2bf(bb.z), f2bf(bb.w)};
            *(uint4*)(h_bf + (size_t)i * 8) = *(const uint4*)tmp;
        }
    }
}

// Parallel bucket allocator (order irrelevant, only disjointness matters).
__global__ void alloc_kernel(const u32* __restrict__ deg, u32* __restrict__ offs,
                             u32* __restrict__ cursor, u32* __restrict__ total, int N) {
    __shared__ u32 wt[4];
    __shared__ u32 bbase;
    int tid = threadIdx.x, lane = tid & 63, wv = tid >> 6;
    int i = blockIdx.x * 256 + tid;
    u32 d = (i < N) ? deg[i] : 0u;
    u32 sc = d;
#pragma unroll
    for (int s = 1; s < 64; s <<= 1) { u32 o = __shfl_up(sc, s); if (lane >= s) sc += o; }
    if (lane == 63) wt[wv] = sc;
    __syncthreads();
    if (tid == 0) bbase = atomicAdd(total, wt[0] + wt[1] + wt[2] + wt[3]);
    __syncthreads();
    u32 wpre = 0;
    for (int w = 0; w < wv; ++w) wpre += wt[w];
    u32 off = bbase + wpre + sc - d;
    if (i < N) { offs[i] = off; cursor[i] = off; }
}

// Bucket-fill, packed metadata: edata[pos] = {src | rel<<18, w_bits}  (8B/edge).
__global__ void fill_kernel(const int* __restrict__ ei, const int* __restrict__ et,
                            const u32* __restrict__ deg_src,
                            const u32* __restrict__ deg_dst,
                            const float* __restrict__ gate,
                            u32* __restrict__ cursor, uint2* __restrict__ edata, int E) {
    int e = blockIdx.x * 256 + threadIdx.x;
    if (e >= E) return;
    int src = ei[e];
    int dst = ei[E + e];
    int rel = et[e];
    float w = gate[rel] * rsqrtf(fmaxf((float)deg_src[src] * (float)deg_dst[dst], 1.0f));
    u32 pos = atomicAdd(&cursor[dst], 1u);
    edata[pos] = make_uint2((u32)src | ((u32)rel << 18), __float_as_uint(w));
}

// 2 nodes per wave (lanes 0-31 = node A, 32-63 = node B; 16B/lane).
// Predicated x4-unrolled edge loop: tail edges use clamped index (cache-hit
// duplicate) with zero weight. Every lane accumulates the full per-node wsum;
// lane l32==0 writes it directly (no cross-lane reduction).
template <int BF>
__global__ __launch_bounds__(256) void agg_kernel(
    const float* __restrict__ h, const u16* __restrict__ h_bf,
    const float* __restrict__ rel_emb, const u16* __restrict__ rel_bf,
    const u32* __restrict__ offs, const u32* __restrict__ deg_dst,
    const uint2* __restrict__ edata,
    u16* __restrict__ agg_bf, float* __restrict__ wsum_arr, int N) {
    int wv = threadIdx.x >> 6, lane = threadIdx.x & 63;
    int half = lane >> 5, l32 = lane & 31;
    int n = (blockIdx.x * 4 + wv) * 2 + half;
    bool valid = n < N;
    u32 off = valid ? offs[n] : 0u;
    u32 dd  = valid ? deg_dst[n] : 0u;
    float acc[8];
#pragma unroll
    for (int j = 0; j < 8; ++j) acc[j] = 0.f;
    float wsum = 0.f;

    for (u32 e = 0; e < dd; e += 4) {
        uint2 d[4];
        uint4 hv[4], rv[4];
        float wq[4];
#pragma unroll
        for (int q = 0; q < 4; ++q) {
            u32 idx = e + q;
            u32 cl = (idx < dd) ? idx : (dd - 1);   // clamp -> dup line, cache hit
            d[q] = edata[off + cl];
            wq[q] = (idx < dd) ? __uint_as_float(d[q].y) : 0.f;
        }
#pragma unroll
        for (int q = 0; q < 4; ++q) {
            u32 src = d[q].x & 0x3FFFFu, rel = d[q].x >> 18;
            if (BF) {
                hv[q] = *(const uint4*)(h_bf + (size_t)src * 256 + l32 * 8);
                rv[q] = *(const uint4*)(rel_bf + (size_t)rel * 256 + l32 * 8);
            } else {
                const float* hp = h + (size_t)src * 256 + l32 * 8;
                const float* rp = rel_emb + (size_t)rel * 256 + l32 * 8;
                float4 hf0 = *(const float4*)hp, hf1 = *(const float4*)(hp + 4);
                float4 rf0 = *(const float4*)rp, rf1 = *(const float4*)(rp + 4);
                u16 th[8] = {f2bf(hf0.x), f2bf(hf0.y), f2bf(hf0.z), f2bf(hf0.w),
                             f2bf(hf1.x), f2bf(hf1.y), f2bf(hf1.z), f2bf(hf1.w)};
                u16 tr[8] = {f2bf(rf0.x), f2bf(rf0.y), f2bf(rf0.z), f2bf(rf0.w),
                             f2bf(rf1.x), f2bf(rf1.y), f2bf(rf1.z), f2bf(rf1.w)};
                hv[q] = *(const uint4*)th;
                rv[q] = *(const uint4*)tr;
            }
        }
#pragma unroll
        for (int q = 0; q < 4; ++q) {
            float w = wq[q];
            u32 hu[4] = {hv[q].x, hv[q].y, hv[q].z, hv[q].w};
            u32 ru[4] = {rv[q].x, rv[q].y, rv[q].z, rv[q].w};
#pragma unroll
            for (int c = 0; c < 4; ++c) {
                acc[c * 2 + 0] += w * bf_lo(hu[c]) * bf_lo(ru[c]);
                acc[c * 2 + 1] += w * bf_hi(hu[c]) * bf_hi(ru[c]);
            }
            wsum += w;
        }
    }

    if (valid) {
        u32 outw[4];
#pragma unroll
        for (int c = 0; c < 4; ++c)
            outw[c] = (u32)f2bf(acc[c * 2]) | ((u32)f2bf(acc[c * 2 + 1]) << 16);
        *(uint4*)(agg_bf + (size_t)n * 512 + l32 * 8) = *(const uint4*)outw;
        if (l32 == 0) wsum_arr[n] = wsum;   // already the full sum per lane
    }
}

// LDS-staged K=512 GEMM. Block = 32 rows x 256 cols; 4 waves, each 32x64
// (acc 2x4 frags; 32KB LDS -> 4 blocks/CU). x=[agg|h] staged async into
// swizzled LDS via global_load_lds (dest linear, per-lane SOURCE pre-
// swizzled). B = fragment-packed Kcomb: each load = 64 lanes x 16B contiguous
// (1KB coalesced burst) from the XCD-local replica.
// out[row][p] = acc + c0[p] + c1[p]*wsum[row].
__global__ __launch_bounds__(256, 4) void gemm_lds_kernel(
    float* __restrict__ dio, const u16* __restrict__ agg_bf,
    const u16* __restrict__ Kcomb, const u16* __restrict__ h_bf,
    const float* __restrict__ wsum_arr,
    const float* __restrict__ c0, const float* __restrict__ c1, int N) {
    __shared__ __align__(16) u16 xs[32 * 512];   // 32 KiB
    const int lane = threadIdx.x & 63;
    const int wv = threadIdx.x >> 6;      // wave owns output cols [wv*64, +64)
    const int l15 = lane & 15;
    const int kg = lane >> 4;             // k-group 0..3
    const int m0 = blockIdx.x * 32;
    const int pbase = wv * 64;
    const int pt0 = wv * 4;               // first B fragment-tile index
    const u16* Kr = Kcomb + (size_t)(blockIdx.x & 7) * 131072;  // XCD replica

    // ---- async stage x=[agg|h] rows -> swizzled LDS (1 row / issue) ----
    {
        int j0 = lane * 8;                       // dest u16 offset in row
#pragma unroll
        for (int i = 0; i < 8; ++i) {
            int m = i * 4 + wv;                  // 0..31
            int row = m0 + m;
            if (row >= N) row = N - 1;           // clamp; masked at store
            int ks = j0 ^ ((m & 7) << 3);        // pre-swizzled source k
            const u16* src = (j0 < 256)
                ? agg_bf + (size_t)row * 512 + ks
                : h_bf + (size_t)row * 256 + (ks - 256);
            gload_lds16(src, &xs[m * 512]);
        }
    }
    __syncthreads();   // drains global_load_lds; also fences in-place d_out use

    f32x4 acc[2][4];
#pragma unroll
    for (int f = 0; f < 2; ++f)
#pragma unroll
        for (int nf = 0; nf < 4; ++nf) acc[f][nf] = (f32x4)(0.f);

    const int swz = (l15 & 7) << 3;
#pragma unroll 4
    for (int k0 = 0; k0 < 512; k0 += 32) {
        int kk = k0 + kg * 8;
        int ksi = k0 >> 5;
        bf16x8 a[2], b[4];
#pragma unroll
        for (int f = 0; f < 2; ++f)
            a[f] = *(const bf16x8*)&xs[(f * 16 + l15) * 512 + (kk ^ swz)];
#pragma unroll
        for (int nf = 0; nf < 4; ++nf)
            b[nf] = *(const bf16x8*)(Kr + (size_t)((pt0 + nf) * 16 + ksi) * 512 + lane * 8);
#pragma unroll
        for (int f = 0; f < 2; ++f)
#pragma unroll
            for (int nf = 0; nf < 4; ++nf)
                acc[f][nf] = __builtin_amdgcn_mfma_f32_16x16x32_bf16(a[f], b[nf], acc[f][nf], 0, 0, 0);
    }

    // ---- epilogue: y = acc + c0[p] + c1[p]*wsum[row] ----
    float b0[4], b1[4];
#pragma unroll
    for (int nf = 0; nf < 4; ++nf) {
        int p = pbase + nf * 16 + l15;
        b0[nf] = c0[p];
        b1[nf] = c1[p];
    }
#pragma unroll
    for (int f = 0; f < 2; ++f) {
#pragma unroll
        for (int r = 0; r < 4; ++r) {
            int row = m0 + f * 16 + kg * 4 + r;
            if (row >= N) continue;
            float wsv = wsum_arr[row];
#pragma unroll
            for (int nf = 0; nf < 4; ++nf) {
                int p = pbase + nf * 16 + l15;
                dio[(size_t)row * 256 + p] = acc[f][nf][r] + b0[nf] + b1[nf] * wsv;
            }
        }
    }
}

// Fallback (no bf16 workspace): register GEMM, packed-B, barrier before epilogue.
__global__ __launch_bounds__(256, 4) void gemm_reg_kernel(
    float* __restrict__ dio, const u16* __restrict__ agg_bf,
    const u16* __restrict__ Kcomb,
    const float* __restrict__ h,
    const float* __restrict__ wsum_arr,
    const float* __restrict__ c0, const float* __restrict__ c1, int N) {
    const int lane = threadIdx.x & 63;
    const int wv = threadIdx.x >> 6;
    const int l15 = lane & 15;
    const int kg = lane >> 4;
    const int m0 = blockIdx.x * 32;
    const int pbase = wv * 64;
    const int pt0 = wv * 4;

    f32x4 acc[2][4];
#pragma unroll
    for (int f = 0; f < 2; ++f)
#pragma unroll
        for (int nf = 0; nf < 4; ++nf) acc[f][nf] = (f32x4)(0.f);

    int rowA[2];
#pragma unroll
    for (int f = 0; f < 2; ++f) {
        int r = m0 + f * 16 + l15;
        rowA[f] = (r < N) ? r : (N - 1);
    }
    const u16* Kr = Kcomb + (size_t)(blockIdx.x & 7) * 131072;

#pragma unroll 2
    for (int k0 = 0; k0 < 256; k0 += 32) {
        int kk = k0 + kg * 8;
        int ksi = k0 >> 5;
        bf16x8 a[2], b[4];
#pragma unroll
        for (int f = 0; f < 2; ++f)
            a[f] = *(const bf16x8*)(agg_bf + (size_t)rowA[f] * 512 + kk);
#pragma unroll
        for (int nf = 0; nf < 4; ++nf)
            b[nf] = *(const bf16x8*)(Kr + (size_t)((pt0 + nf) * 16 + ksi) * 512 + lane * 8);
#pragma unroll
        for (int f = 0; f < 2; ++f)
#pragma unroll
            for (int nf = 0; nf < 4; ++nf)
                acc[f][nf] = __builtin_amdgcn_mfma_f32_16x16x32_bf16(a[f], b[nf], acc[f][nf], 0, 0, 0);
    }
#pragma unroll 2
    for (int k0 = 256; k0 < 512; k0 += 32) {
        int kh = (k0 - 256) + kg * 8;
        int ksi = k0 >> 5;
        bf16x8 a[2], b[4];
#pragma unroll
        for (int f = 0; f < 2; ++f) {
            const float* hp = h + (size_t)rowA[f] * 256 + kh;
            float4 f0 = *(const float4*)hp, f1 = *(const float4*)(hp + 4);
            u16 tmp[8] = {f2bf(f0.x), f2bf(f0.y), f2bf(f0.z), f2bf(f0.w),
                          f2bf(f1.x), f2bf(f1.y), f2bf(f1.z), f2bf(f1.w)};
            a[f] = *(const bf16x8*)tmp;
        }
#pragma unroll
        for (int nf = 0; nf < 4; ++nf)
            b[nf] = *(const bf16x8*)(Kr + (size_t)((pt0 + nf) * 16 + ksi) * 512 + lane * 8);
#pragma unroll
        for (int f = 0; f < 2; ++f)
#pragma unroll
            for (int nf = 0; nf < 4; ++nf)
                acc[f][nf] = __builtin_amdgcn_mfma_f32_16x16x32_bf16(a[f], b[nf], acc[f][nf], 0, 0, 0);
    }

    __syncthreads();   // all waves done reading agg before in-place overwrite

    float b0[4], b1[4];
#pragma unroll
    for (int nf = 0; nf < 4; ++nf) {
        int p = pbase + nf * 16 + l15;
        b0[nf] = c0[p];
        b1[nf] = c1[p];
    }
#pragma unroll
    for (int f = 0; f < 2; ++f) {
#pragma unroll
        for (int r = 0; r < 4; ++r) {
            int row = m0 + f * 16 + kg * 4 + r;
            if (row >= N) continue;
            float wsv = wsum_arr[row];
#pragma unroll
            for (int nf = 0; nf < 4; ++nf) {
                int p = pbase + nf * 16 + l15;
                dio[(size_t)row * 256 + p] = acc[f][nf][r] + b0[nf] + b1[nf] * wsv;
            }
        }
    }
}

static inline size_t align4(size_t x) { return (x + 3) & ~(size_t)3; }

extern "C" void kernel_launch(void* const* d_in, const int* in_sizes, int n_in,
                              void* d_out, int out_size, void* d_ws, size_t ws_size,
                              hipStream_t stream) {
    const float* h       = (const float*)d_in[0];
    const int*   ei      = (const int*)d_in[1];   // (2,E) row-major
    const int*   et      = (const int*)d_in[2];
    const float* rel_emb = (const float*)d_in[3];
    const float* msg_w   = (const float*)d_in[4];
    const float* msg_b   = (const float*)d_in[5];
    const float* upd_w   = (const float*)d_in[6];
    const float* upd_b   = (const float*)d_in[7];
    const float* gate_w  = (const float*)d_in[8];
    const float* gate_b  = (const float*)d_in[9];

    const int N = in_sizes[0] / 256;
    const int E = in_sizes[2];
    const int R = in_sizes[3] / 256;

    // workspace layout (u32 units); total+deg_src+deg_dst contiguous for memset
    u32* ws = (u32*)d_ws;
    size_t o = 0;
    u32* total    = ws + o; o += 4;
    u32* deg_src  = ws + o; o += align4((size_t)N);
    u32* deg_dst  = ws + o; o += align4((size_t)N);
    u32* offs     = ws + o; o += align4((size_t)N);
    u32* cursor   = ws + o; o += align4((size_t)N);
    float* wsum   = (float*)(ws + o); o += align4((size_t)N);
    float* gate   = (float*)(ws + o); o += align4((size_t)R);
    uint2* edata  = (uint2*)(ws + o); o += (size_t)2 * E;
    u16* Kcomb    = (u16*)(ws + o); o += 524288;    // 8 x 256KB fragment-packed
    float* c0     = (float*)(ws + o); o += 256;
    float* c1     = (float*)(ws + o); o += 256;
    size_t need_base = o;
    u16* h_bf     = (u16*)(ws + o); o += (size_t)N * 128;
    u16* rel_bf   = (u16*)(ws + o); o += (size_t)R * 128;
    size_t need_bf = o;

    if (ws_size < need_base * 4) return;  // insufficient scratch -> fail loudly
    const bool use_bf = (ws_size >= need_bf * 4);

    float* out = (float*)d_out;
    u16* agg_bf = (u16*)d_out;   // bf16 rows at u16 stride 512 (half of each slot)

    // zero total + degree counters (contiguous)
    hipMemsetAsync(total, 0, (4 + 2 * align4((size_t)N)) * 4, stream);

    const int nbDeg  = (E + 255) / 256;
    const int nbGate = (R + 3) / 4;
    const int nbRel  = use_bf ? (R * 32 + 255) / 256 : 0;
    const int nbH    = use_bf ? 1024 : 0;
    const int nbPrep = 256 + nbDeg + nbGate + nbRel + nbH;

    if (use_bf) {
        prep_kernel<1><<<nbPrep, 256, 0, stream>>>(
            msg_w, upd_w, upd_b, msg_b, rel_emb, gate_w, gate_b, h, ei, E,
            deg_src, deg_dst, gate, Kcomb, c0, c1, h_bf, rel_bf,
            N, R, nbDeg, nbGate, nbRel, nbH);
    } else {
        prep_kernel<0><<<nbPrep, 256, 0, stream>>>(
            msg_w, upd_w, upd_b, msg_b, rel_emb, gate_w, gate_b, h, ei, E,
            deg_src, deg_dst, gate, Kcomb, c0, c1, h_bf, rel_bf,
            N, R, nbDeg, nbGate, nbRel, nbH);
    }
    alloc_kernel<<<(N + 255) / 256, 256, 0, stream>>>(deg_dst, offs, cursor, total, N);
    fill_kernel<<<(E + 255) / 256, 256, 0, stream>>>(ei, et, deg_src, deg_dst, gate,
                                                     cursor, edata, E);
    if (use_bf) {
        agg_kernel<1><<<(N + 7) / 8, 256, 0, stream>>>(h, h_bf, rel_emb, rel_bf, offs,
                                                       deg_dst, edata, agg_bf, wsum, N);
        gemm_lds_kernel<<<(N + 31) / 32, 256, 0, stream>>>(out, agg_bf, Kcomb, h_bf,
                                                           wsum, c0, c1, N);
    } else {
        agg_kernel<0><<<(N + 7) / 8, 256, 0, stream>>>(h, h_bf, rel_emb, rel_bf, offs,
                                                       deg_dst, edata, agg_bf, wsum, N);
        gemm_reg_kernel<<<(N + 31) / 32, 256, 0, stream>>>(out, agg_bf, Kcomb, h,
                                                           wsum, c0, c1, N);
    }
}

// Round 13
// 223.936 us; speedup vs baseline: 1.5959x; 1.0635x over previous
//
#include <hip/hip_runtime.h>
#include <math.h>

typedef unsigned int u32;
typedef unsigned short u16;
typedef __attribute__((ext_vector_type(8))) short bf16x8;   // 8 bf16 in 4 VGPRs
typedef __attribute__((ext_vector_type(4))) float f32x4;

#define GLOBAL_AS __attribute__((address_space(1)))
#define LDS_AS __attribute__((address_space(3)))

__device__ __forceinline__ void gload_lds16(const void* g, void* s) {
    __builtin_amdgcn_global_load_lds((const GLOBAL_AS void*)g, (LDS_AS void*)s, 16, 0, 0);
}

__device__ inline u16 f2bf(float x) {  // round-to-nearest-even
    union { float f; u32 u; } v; v.f = x;
    u32 r = v.u + 0x7FFFu + ((v.u >> 16) & 1u);
    return (u16)(r >> 16);
}
__device__ inline float bf2f(u16 x) { return __uint_as_float((u32)x << 16); }
__device__ inline float bf_lo(u32 u) { return __uint_as_float(u << 16); }
__device__ inline float bf_hi(u32 u) { return __uint_as_float(u & 0xffff0000u); }

// Clifford sign/slot closed forms (replaces s_tab/g_tab; avoids scratch):
//   s = ob ^ ib ;  g = -1 iff (ob != 3 && ib == (3 ^ (ob & 1)))
__device__ __forceinline__ int cs_s(int ob, int ib) { return ob ^ ib; }
__device__ __forceinline__ float cs_g(int ob, int ib) {
    return ((ob != 3) && (ib == (3 ^ (ob & 1)))) ? -1.f : 1.f;
}

// ---------------------------------------------------------------------------
// Clifford GNN message passing, fully linearized:
//   agg[n] = sum_e w_e*(h[src] .* r[rel]),  w_e = gate(rel)*norm(e)
//   out    = (Ku.Km).agg + Ku.h + ws*(Ku.msg_b) + upd_b
// Pipeline: memset -> kbuild (Kcomb via LDS-staged msg_w, <=5us) ->
// prep2 (fused: tobf_h FIRST + degree + gate + tobf_rel) -> alloc -> fill ->
// agg -> gemm.  Round-13: round-12's fused builder was a ~90us straggler
// (256-step global-latency-serial dot product); now it reads only LDS.
// ---------------------------------------------------------------------------

// Block p builds output-permuted row p of Kcomb (fragment-packed, 8 replicas)
// + c0[p], c1[p].  msg_w staged to LDS as bf16 (32KB) so the 256-step dot
// product never touches global memory.
__global__ __launch_bounds__(256) void kbuild_kernel(
    const float* __restrict__ msg_w, const float* __restrict__ upd_w,
    const float* __restrict__ upd_b, const float* __restrict__ msg_b,
    u16* __restrict__ Kcomb, float* __restrict__ c0, float* __restrict__ c1) {
    __shared__ __align__(16) u16 ms[16384];   // msg_w as bf16, 32KB
    __shared__ float U_s[256];
    __shared__ float wred[4];
    int p = blockIdx.x;
    int j = (p & 3) * 64 + (p >> 2);
    int tid = threadIdx.x;
    // stage msg_w -> bf16 LDS (coalesced: 8 chunks of 8 floats per thread)
#pragma unroll
    for (int i = 0; i < 8; ++i) {
        int c8 = i * 256 + tid;                // chunk of 8 elements
        const float* p8 = msg_w + (size_t)c8 * 8;
        float4 a = *(const float4*)(p8);
        float4 b = *(const float4*)(p8 + 4);
        u16 tmp[8] = {f2bf(a.x), f2bf(a.y), f2bf(a.z), f2bf(a.w),
                      f2bf(b.x), f2bf(b.y), f2bf(b.z), f2bf(b.w)};
        *(uint4*)&ms[c8 * 8] = *(const uint4*)tmp;
    }
    int ib = tid >> 6, ic = tid & 63;
    {
        int obu = j >> 6;
        U_s[tid] = cs_g(obu, ib) * upd_w[cs_s(obu, ib) * 4096 + (j & 63) * 64 + ic];
    }
    __syncthreads();
    float acc = 0.f;
#pragma unroll
    for (int ob = 0; ob < 4; ++ob) {
        int s = cs_s(ob, ib);
        float gg = cs_g(ob, ib);
        const u16* mp = ms + s * 4096 + ic;
        const float* us = U_s + ob * 64;
        float a0 = 0.f;
#pragma unroll 8
        for (int oc = 0; oc < 64; ++oc) a0 += us[oc] * bf2f(mp[oc * 64]);
        acc += gg * a0;
    }
    u16 vA = f2bf(acc);          // element (p, k=tid)
    u16 vU = f2bf(U_s[tid]);     // element (p, k=tid+256)
    int pt = p >> 4, pl = p & 15;
    int kgA = (tid >> 3) & 3, elA = tid & 7;
    size_t addrA = (size_t)(pt * 16 + (tid >> 5)) * 512 + (kgA * 16 + pl) * 8 + elA;
    int ku = tid + 256;
    size_t addrU = (size_t)(pt * 16 + (ku >> 5)) * 512 + (kgA * 16 + pl) * 8 + elA;
#pragma unroll
    for (int r = 0; r < 8; ++r) {        // 8 replicas (one per XCD's L2)
        Kcomb[(size_t)r * 131072 + addrA] = vA;
        Kcomb[(size_t)r * 131072 + addrU] = vU;
    }
    float part = U_s[tid] * msg_b[tid];
    int lane = tid & 63, wv = tid >> 6;
#pragma unroll
    for (int d = 32; d > 0; d >>= 1) part += __shfl_down(part, d);
    if (lane == 0) wred[wv] = part;
    __syncthreads();
    if (tid == 0) { c1[p] = wred[0] + wred[1] + wred[2] + wred[3]; c0[p] = upd_b[j]; }
}

// Fused streaming prep. Block ranges (BW-heavy h-conversion FIRST):
//  [0, nbH)      : h -> h_bf (grid-stride)
//  [.., +nbDeg)  : degree atomics
//  [.., +nbGate) : gate[r] (4 rel/block)
//  [.., +nbRel)  : rel_emb -> rel_bf
template <int BF>
__global__ __launch_bounds__(256) void prep2_kernel(
    const float* __restrict__ h, const float* __restrict__ rel_emb,
    const float* __restrict__ gate_w, const float* __restrict__ gate_b,
    const int* __restrict__ ei, int E,
    u32* __restrict__ deg_src, u32* __restrict__ deg_dst,
    float* __restrict__ gate, u16* __restrict__ h_bf, u16* __restrict__ rel_bf,
    int N, int R, int nbH, int nbDeg, int nbGate, int nbRel) {
    int b = blockIdx.x;
    int tid = threadIdx.x;
    if (BF && b < nbH) {
        int n8 = N * 32;
        for (int i = b * 256 + tid; i < n8; i += nbH * 256) {
            const float* p8 = h + (size_t)i * 8;
            float4 a = *(const float4*)(p8);
            float4 bb = *(const float4*)(p8 + 4);
            u16 tmp[8] = {f2bf(a.x), f2bf(a.y), f2bf(a.z), f2bf(a.w),
                          f2bf(bb.x), f2bf(bb.y), f2bf(bb.z), f2bf(bb.w)};
            *(uint4*)(h_bf + (size_t)i * 8) = *(const uint4*)tmp;
        }
        return;
    }
    b -= BF ? nbH : 0;
    if (b < nbDeg) {
        int e = b * 256 + tid;
        if (e < E) {
            atomicAdd(&deg_src[ei[e]], 1u);
            atomicAdd(&deg_dst[ei[E + e]], 1u);
        }
        return;
    }
    b -= nbDeg;
    if (b < nbGate) {
        int wv = tid >> 6, lane = tid & 63;
        int r = b * 4 + wv;
        if (r >= R) return;
        float4 rv = *(const float4*)(rel_emb + (size_t)r * 256 + lane * 4);
        float s = 0.f;
        float rvv[4] = {rv.x, rv.y, rv.z, rv.w};
#pragma unroll
        for (int c = 0; c < 4; ++c) {
            int jj = lane * 4 + c;
            s += rvv[c] * gate_w[(jj & 63) * 4 + (jj >> 6)];
        }
#pragma unroll
        for (int d = 32; d > 0; d >>= 1) s += __shfl_down(s, d);
        if (lane == 0) gate[r] = 1.0f / (1.0f + expf(-(s + gate_b[0])));
        return;
    }
    b -= nbGate;
    if (BF && b < nbRel) {
        int i = b * 256 + tid;
        if (i < R * 32) {
            const float* p8 = rel_emb + (size_t)i * 8;
            float4 a = *(const float4*)(p8);
            float4 bb = *(const float4*)(p8 + 4);
            u16 tmp[8] = {f2bf(a.x), f2bf(a.y), f2bf(a.z), f2bf(a.w),
                          f2bf(bb.x), f2bf(bb.y), f2bf(bb.z), f2bf(bb.w)};
            *(uint4*)(rel_bf + (size_t)i * 8) = *(const uint4*)tmp;
        }
    }
}

// Parallel bucket allocator (order irrelevant, only disjointness matters).
__global__ void alloc_kernel(const u32* __restrict__ deg, u32* __restrict__ offs,
                             u32* __restrict__ cursor, u32* __restrict__ total, int N) {
    __shared__ u32 wt[4];
    __shared__ u32 bbase;
    int tid = threadIdx.x, lane = tid & 63, wv = tid >> 6;
    int i = blockIdx.x * 256 + tid;
    u32 d = (i < N) ? deg[i] : 0u;
    u32 sc = d;
#pragma unroll
    for (int s = 1; s < 64; s <<= 1) { u32 o = __shfl_up(sc, s); if (lane >= s) sc += o; }
    if (lane == 63) wt[wv] = sc;
    __syncthreads();
    if (tid == 0) bbase = atomicAdd(total, wt[0] + wt[1] + wt[2] + wt[3]);
    __syncthreads();
    u32 wpre = 0;
    for (int w = 0; w < wv; ++w) wpre += wt[w];
    u32 off = bbase + wpre + sc - d;
    if (i < N) { offs[i] = off; cursor[i] = off; }
}

// Bucket-fill, packed metadata: edata[pos] = {src | rel<<18, w_bits}  (8B/edge).
__global__ void fill_kernel(const int* __restrict__ ei, const int* __restrict__ et,
                            const u32* __restrict__ deg_src,
                            const u32* __restrict__ deg_dst,
                            const float* __restrict__ gate,
                            u32* __restrict__ cursor, uint2* __restrict__ edata, int E) {
    int e = blockIdx.x * 256 + threadIdx.x;
    if (e >= E) return;
    int src = ei[e];
    int dst = ei[E + e];
    int rel = et[e];
    float w = gate[rel] * rsqrtf(fmaxf((float)deg_src[src] * (float)deg_dst[dst], 1.0f));
    u32 pos = atomicAdd(&cursor[dst], 1u);
    edata[pos] = make_uint2((u32)src | ((u32)rel << 18), __float_as_uint(w));
}

// 2 nodes per wave (lanes 0-31 = node A, 32-63 = node B; 16B/lane).
// Predicated x4-unrolled edge loop: tail edges use clamped index (cache-hit
// duplicate) with zero weight. Every lane accumulates the full per-node wsum;
// lane l32==0 writes it directly (no cross-lane reduction).
template <int BF>
__global__ __launch_bounds__(256) void agg_kernel(
    const float* __restrict__ h, const u16* __restrict__ h_bf,
    const float* __restrict__ rel_emb, const u16* __restrict__ rel_bf,
    const u32* __restrict__ offs, const u32* __restrict__ deg_dst,
    const uint2* __restrict__ edata,
    u16* __restrict__ agg_bf, float* __restrict__ wsum_arr, int N) {
    int wv = threadIdx.x >> 6, lane = threadIdx.x & 63;
    int half = lane >> 5, l32 = lane & 31;
    int n = (blockIdx.x * 4 + wv) * 2 + half;
    bool valid = n < N;
    u32 off = valid ? offs[n] : 0u;
    u32 dd  = valid ? deg_dst[n] : 0u;
    float acc[8];
#pragma unroll
    for (int j = 0; j < 8; ++j) acc[j] = 0.f;
    float wsum = 0.f;

    for (u32 e = 0; e < dd; e += 4) {
        uint2 d[4];
        uint4 hv[4], rv[4];
        float wq[4];
#pragma unroll
        for (int q = 0; q < 4; ++q) {
            u32 idx = e + q;
            u32 cl = (idx < dd) ? idx : (dd - 1);   // clamp -> dup line, cache hit
            d[q] = edata[off + cl];
            wq[q] = (idx < dd) ? __uint_as_float(d[q].y) : 0.f;
        }
#pragma unroll
        for (int q = 0; q < 4; ++q) {
            u32 src = d[q].x & 0x3FFFFu, rel = d[q].x >> 18;
            if (BF) {
                hv[q] = *(const uint4*)(h_bf + (size_t)src * 256 + l32 * 8);
                rv[q] = *(const uint4*)(rel_bf + (size_t)rel * 256 + l32 * 8);
            } else {
                const float* hp = h + (size_t)src * 256 + l32 * 8;
                const float* rp = rel_emb + (size_t)rel * 256 + l32 * 8;
                float4 hf0 = *(const float4*)hp, hf1 = *(const float4*)(hp + 4);
                float4 rf0 = *(const float4*)rp, rf1 = *(const float4*)(rp + 4);
                u16 th[8] = {f2bf(hf0.x), f2bf(hf0.y), f2bf(hf0.z), f2bf(hf0.w),
                             f2bf(hf1.x), f2bf(hf1.y), f2bf(hf1.z), f2bf(hf1.w)};
                u16 tr[8] = {f2bf(rf0.x), f2bf(rf0.y), f2bf(rf0.z), f2bf(rf0.w),
                             f2bf(rf1.x), f2bf(rf1.y), f2bf(rf1.z), f2bf(rf1.w)};
                hv[q] = *(const uint4*)th;
                rv[q] = *(const uint4*)tr;
            }
        }
#pragma unroll
        for (int q = 0; q < 4; ++q) {
            float w = wq[q];
            u32 hu[4] = {hv[q].x, hv[q].y, hv[q].z, hv[q].w};
            u32 ru[4] = {rv[q].x, rv[q].y, rv[q].z, rv[q].w};
#pragma unroll
            for (int c = 0; c < 4; ++c) {
                acc[c * 2 + 0] += w * bf_lo(hu[c]) * bf_lo(ru[c]);
                acc[c * 2 + 1] += w * bf_hi(hu[c]) * bf_hi(ru[c]);
            }
            wsum += w;
        }
    }

    if (valid) {
        u32 outw[4];
#pragma unroll
        for (int c = 0; c < 4; ++c)
            outw[c] = (u32)f2bf(acc[c * 2]) | ((u32)f2bf(acc[c * 2 + 1]) << 16);
        *(uint4*)(agg_bf + (size_t)n * 512 + l32 * 8) = *(const uint4*)outw;
        if (l32 == 0) wsum_arr[n] = wsum;   // already the full sum per lane
    }
}

// LDS-staged K=512 GEMM. Block = 32 rows x 256 cols; 4 waves, each 32x64
// (acc 2x4 frags; 32KB LDS -> 4 blocks/CU). x=[agg|h] staged async into
// swizzled LDS via global_load_lds (dest linear, per-lane SOURCE pre-
// swizzled). B = fragment-packed Kcomb: each load = 64 lanes x 16B contiguous
// (1KB coalesced burst) from the XCD-local replica.
// out[row][p] = acc + c0[p] + c1[p]*wsum[row].
__global__ __launch_bounds__(256, 4) void gemm_lds_kernel(
    float* __restrict__ dio, const u16* __restrict__ agg_bf,
    const u16* __restrict__ Kcomb, const u16* __restrict__ h_bf,
    const float* __restrict__ wsum_arr,
    const float* __restrict__ c0, const float* __restrict__ c1, int N) {
    __shared__ __align__(16) u16 xs[32 * 512];   // 32 KiB
    const int lane = threadIdx.x & 63;
    const int wv = threadIdx.x >> 6;      // wave owns output cols [wv*64, +64)
    const int l15 = lane & 15;
    const int kg = lane >> 4;             // k-group 0..3
    const int m0 = blockIdx.x * 32;
    const int pbase = wv * 64;
    const int pt0 = wv * 4;               // first B fragment-tile index
    const u16* Kr = Kcomb + (size_t)(blockIdx.x & 7) * 131072;  // XCD replica

    // ---- async stage x=[agg|h] rows -> swizzled LDS (1 row / issue) ----
    {
        int j0 = lane * 8;                       // dest u16 offset in row
#pragma unroll
        for (int i = 0; i < 8; ++i) {
            int m = i * 4 + wv;                  // 0..31
            int row = m0 + m;
            if (row >= N) row = N - 1;           // clamp; masked at store
            int ks = j0 ^ ((m & 7) << 3);        // pre-swizzled source k
            const u16* src = (j0 < 256)
                ? agg_bf + (size_t)row * 512 + ks
                : h_bf + (size_t)row * 256 + (ks - 256);
            gload_lds16(src, &xs[m * 512]);
        }
    }
    __syncthreads();   // drains global_load_lds; also fences in-place d_out use

    f32x4 acc[2][4];
#pragma unroll
    for (int f = 0; f < 2; ++f)
#pragma unroll
        for (int nf = 0; nf < 4; ++nf) acc[f][nf] = (f32x4)(0.f);

    const int swz = (l15 & 7) << 3;
#pragma unroll 4
    for (int k0 = 0; k0 < 512; k0 += 32) {
        int kk = k0 + kg * 8;
        int ksi = k0 >> 5;
        bf16x8 a[2], b[4];
#pragma unroll
        for (int f = 0; f < 2; ++f)
            a[f] = *(const bf16x8*)&xs[(f * 16 + l15) * 512 + (kk ^ swz)];
#pragma unroll
        for (int nf = 0; nf < 4; ++nf)
            b[nf] = *(const bf16x8*)(Kr + (size_t)((pt0 + nf) * 16 + ksi) * 512 + lane * 8);
#pragma unroll
        for (int f = 0; f < 2; ++f)
#pragma unroll
            for (int nf = 0; nf < 4; ++nf)
                acc[f][nf] = __builtin_amdgcn_mfma_f32_16x16x32_bf16(a[f], b[nf], acc[f][nf], 0, 0, 0);
    }

    // ---- epilogue: y = acc + c0[p] + c1[p]*wsum[row] ----
    float b0[4], b1[4];
#pragma unroll
    for (int nf = 0; nf < 4; ++nf) {
        int p = pbase + nf * 16 + l15;
        b0[nf] = c0[p];
        b1[nf] = c1[p];
    }
#pragma unroll
    for (int f = 0; f < 2; ++f) {
#pragma unroll
        for (int r = 0; r < 4; ++r) {
            int row = m0 + f * 16 + kg * 4 + r;
            if (row >= N) continue;
            float wsv = wsum_arr[row];
#pragma unroll
            for (int nf = 0; nf < 4; ++nf) {
                int p = pbase + nf * 16 + l15;
                dio[(size_t)row * 256 + p] = acc[f][nf][r] + b0[nf] + b1[nf] * wsv;
            }
        }
    }
}

// Fallback (no bf16 workspace): register GEMM, packed-B, barrier before epilogue.
__global__ __launch_bounds__(256, 4) void gemm_reg_kernel(
    float* __restrict__ dio, const u16* __restrict__ agg_bf,
    const u16* __restrict__ Kcomb,
    const float* __restrict__ h,
    const float* __restrict__ wsum_arr,
    const float* __restrict__ c0, const float* __restrict__ c1, int N) {
    const int lane = threadIdx.x & 63;
    const int wv = threadIdx.x >> 6;
    const int l15 = lane & 15;
    const int kg = lane >> 4;
    const int m0 = blockIdx.x * 32;
    const int pbase = wv * 64;
    const int pt0 = wv * 4;

    f32x4 acc[2][4];
#pragma unroll
    for (int f = 0; f < 2; ++f)
#pragma unroll
        for (int nf = 0; nf < 4; ++nf) acc[f][nf] = (f32x4)(0.f);

    int rowA[2];
#pragma unroll
    for (int f = 0; f < 2; ++f) {
        int r = m0 + f * 16 + l15;
        rowA[f] = (r < N) ? r : (N - 1);
    }
    const u16* Kr = Kcomb + (size_t)(blockIdx.x & 7) * 131072;

#pragma unroll 2
    for (int k0 = 0; k0 < 256; k0 += 32) {
        int kk = k0 + kg * 8;
        int ksi = k0 >> 5;
        bf16x8 a[2], b[4];
#pragma unroll
        for (int f = 0; f < 2; ++f)
            a[f] = *(const bf16x8*)(agg_bf + (size_t)rowA[f] * 512 + kk);
#pragma unroll
        for (int nf = 0; nf < 4; ++nf)
            b[nf] = *(const bf16x8*)(Kr + (size_t)((pt0 + nf) * 16 + ksi) * 512 + lane * 8);
#pragma unroll
        for (int f = 0; f < 2; ++f)
#pragma unroll
            for (int nf = 0; nf < 4; ++nf)
                acc[f][nf] = __builtin_amdgcn_mfma_f32_16x16x32_bf16(a[f], b[nf], acc[f][nf], 0, 0, 0);
    }
#pragma unroll 2
    for (int k0 = 256; k0 < 512; k0 += 32) {
        int kh = (k0 - 256) + kg * 8;
        int ksi = k0 >> 5;
        bf16x8 a[2], b[4];
#pragma unroll
        for (int f = 0; f < 2; ++f) {
            const float* hp = h + (size_t)rowA[f] * 256 + kh;
            float4 f0 = *(const float4*)hp, f1 = *(const float4*)(hp + 4);
            u16 tmp[8] = {f2bf(f0.x), f2bf(f0.y), f2bf(f0.z), f2bf(f0.w),
                          f2bf(f1.x), f2bf(f1.y), f2bf(f1.z), f2bf(f1.w)};
            a[f] = *(const bf16x8*)tmp;
        }
#pragma unroll
        for (int nf = 0; nf < 4; ++nf)
            b[nf] = *(const bf16x8*)(Kr + (size_t)((pt0 + nf) * 16 + ksi) * 512 + lane * 8);
#pragma unroll
        for (int f = 0; f < 2; ++f)
#pragma unroll
            for (int nf = 0; nf < 4; ++nf)
                acc[f][nf] = __builtin_amdgcn_mfma_f32_16x16x32_bf16(a[f], b[nf], acc[f][nf], 0, 0, 0);
    }

    __syncthreads();   // all waves done reading agg before in-place overwrite

    float b0[4], b1[4];
#pragma unroll
    for (int nf = 0; nf < 4; ++nf) {
        int p = pbase + nf * 16 + l15;
        b0[nf] = c0[p];
        b1[nf] = c1[p];
    }
#pragma unroll
    for (int f = 0; f < 2; ++f) {
#pragma unroll
        for (int r = 0; r < 4; ++r) {
            int row = m0 + f * 16 + kg * 4 + r;
            if (row >= N) continue;
            float wsv = wsum_arr[row];
#pragma unroll
            for (int nf = 0; nf < 4; ++nf) {
                int p = pbase + nf * 16 + l15;
                dio[(size_t)row * 256 + p] = acc[f][nf][r] + b0[nf] + b1[nf] * wsv;
            }
        }
    }
}

static inline size_t align4(size_t x) { return (x + 3) & ~(size_t)3; }

extern "C" void kernel_launch(void* const* d_in, const int* in_sizes, int n_in,
                              void* d_out, int out_size, void* d_ws, size_t ws_size,
                              hipStream_t stream) {
    const float* h       = (const float*)d_in[0];
    const int*   ei      = (const int*)d_in[1];   // (2,E) row-major
    const int*   et      = (const int*)d_in[2];
    const float* rel_emb = (const float*)d_in[3];
    const float* msg_w   = (const float*)d_in[4];
    const float* msg_b   = (const float*)d_in[5];
    const float* upd_w   = (const float*)d_in[6];
    const float* upd_b   = (const float*)d_in[7];
    const float* gate_w  = (const float*)d_in[8];
    const float* gate_b  = (const float*)d_in[9];

    const int N = in_sizes[0] / 256;
    const int E = in_sizes[2];
    const int R = in_sizes[3] / 256;

    // workspace layout (u32 units); total+deg_src+deg_dst contiguous for memset
    u32* ws = (u32*)d_ws;
    size_t o = 0;
    u32* total    = ws + o; o += 4;
    u32* deg_src  = ws + o; o += align4((size_t)N);
    u32* deg_dst  = ws + o; o += align4((size_t)N);
    u32* offs     = ws + o; o += align4((size_t)N);
    u32* cursor   = ws + o; o += align4((size_t)N);
    float* wsum   = (float*)(ws + o); o += align4((size_t)N);
    float* gate   = (float*)(ws + o); o += align4((size_t)R);
    uint2* edata  = (uint2*)(ws + o); o += (size_t)2 * E;
    u16* Kcomb    = (u16*)(ws + o); o += 524288;    // 8 x 256KB fragment-packed
    float* c0     = (float*)(ws + o); o += 256;
    float* c1     = (float*)(ws + o); o += 256;
    size_t need_base = o;
    u16* h_bf     = (u16*)(ws + o); o += (size_t)N * 128;
    u16* rel_bf   = (u16*)(ws + o); o += (size_t)R * 128;
    size_t need_bf = o;

    if (ws_size < need_base * 4) return;  // insufficient scratch -> fail loudly
    const bool use_bf = (ws_size >= need_bf * 4);

    float* out = (float*)d_out;
    u16* agg_bf = (u16*)d_out;   // bf16 rows at u16 stride 512 (half of each slot)

    // zero total + degree counters (contiguous)
    hipMemsetAsync(total, 0, (4 + 2 * align4((size_t)N)) * 4, stream);

    kbuild_kernel<<<256, 256, 0, stream>>>(msg_w, upd_w, upd_b, msg_b, Kcomb, c0, c1);

    const int nbH    = use_bf ? 1024 : 0;
    const int nbDeg  = (E + 255) / 256;
    const int nbGate = (R + 3) / 4;
    const int nbRel  = use_bf ? (R * 32 + 255) / 256 : 0;
    const int nbPrep = nbH + nbDeg + nbGate + nbRel;

    if (use_bf) {
        prep2_kernel<1><<<nbPrep, 256, 0, stream>>>(
            h, rel_emb, gate_w, gate_b, ei, E, deg_src, deg_dst, gate,
            h_bf, rel_bf, N, R, nbH, nbDeg, nbGate, nbRel);
    } else {
        prep2_kernel<0><<<nbPrep, 256, 0, stream>>>(
            h, rel_emb, gate_w, gate_b, ei, E, deg_src, deg_dst, gate,
            h_bf, rel_bf, N, R, nbH, nbDeg, nbGate, nbRel);
    }
    alloc_kernel<<<(N + 255) / 256, 256, 0, stream>>>(deg_dst, offs, cursor, total, N);
    fill_kernel<<<(E + 255) / 256, 256, 0, stream>>>(ei, et, deg_src, deg_dst, gate,
                                                     cursor, edata, E);
    if (use_bf) {
        agg_kernel<1><<<(N + 7) / 8, 256, 0, stream>>>(h, h_bf, rel_emb, rel_bf, offs,
                                                       deg_dst, edata, agg_bf, wsum, N);
        gemm_lds_kernel<<<(N + 31) / 32, 256, 0, stream>>>(out, agg_bf, Kcomb, h_bf,
                                                           wsum, c0, c1, N);
    } else {
        agg_kernel<0><<<(N + 7) / 8, 256, 0, stream>>>(h, h_bf, rel_emb, rel_bf, offs,
                                                       deg_dst, edata, agg_bf, wsum, N);
        gemm_reg_kernel<<<(N + 31) / 32, 256, 0, stream>>>(out, agg_bf, Kcomb, h,
                                                           wsum, c0, c1, N);
    }
}